// Round 6
// baseline (501.817 us; speedup 1.0000x reference)
//
#include <hip/hip_runtime.h>
#include <hip/hip_bf16.h>

typedef unsigned int  uint32;
typedef unsigned short ushort16;

#define B_TOTAL 65536
#define NN 17

typedef __bf16 bf16x8 __attribute__((ext_vector_type(8)));
typedef float  f32x4  __attribute__((ext_vector_type(4)));

// ---- fixed normalized adjacency (from EDGES in the reference) ----
static constexpr int   CNT[NN]    = {2,0,0,0,0,4,4,2,2,1,1,3,3,2,2,1,1};
static constexpr int   NBR[NN][4] = {
  {5,6,0,0},{0,0,0,0},{0,0,0,0},{0,0,0,0},{0,0,0,0},
  {7,6,11,0},{8,5,12,0},{5,9,0,0},{6,10,0,0},{7,0,0,0},{8,0,0,0},
  {5,12,13,0},{6,11,14,0},{11,15,0,0},{12,16,0,0},{13,0,0,0},{14,0,0,0}};
static constexpr float INVDEG[NN] = {0.5f,0.f,0.f,0.f,0.f,0.25f,0.25f,0.5f,0.5f,1.f,1.f,
  0.33333333333333333f,0.33333333333333333f,0.5f,0.5f,1.f,1.f};

// ---- workspace layout (bytes) ----
#define S_BYTES   ((size_t)B_TOTAL * 1088 * 2)
#define STATS_OFF S_BYTES
#define W1_OFF    (STATS_OFF + 40960)
#define W2_OFF    (W1_OFF + (size_t)278528*2)
#define WGT_OFF   (W2_OFF + (size_t)65536)   // 4 x 4096 bf16: W1hi, W1lo, W2hi, W2lo

// stats float offsets:
//   0     sum1[32 slots][32]      1024  sq1[32][32]
//   2048  sum2[32][32]            3072  sq2[32][32]
//   4096  sc1[32]  4128 sf1[32]   4160  sc2[32]  4192 sf2[32]
//   4224  colsum2[64]             4288  SH[1088]

__device__ inline ushort16 f2bfu(float f){
  union { __hip_bfloat16 h; ushort16 u; } c; c.h = __float2bfloat16(f); return c.u;
}

__device__ inline f32x4 MFMA(bf16x8 a, bf16x8 b, f32x4 c){
  return __builtin_amdgcn_mfma_f32_16x16x32_bf16(a, b, c, 0, 0, 0);
}

// encoder + normalized-adjacency aggregate for one batch row, one feature dim e.
__device__ inline void enc_agg(const float* __restrict__ xb,
                               float we0, float we1, float be, float* s1){
  float h[NN];
  #pragma unroll
  for (int n = 0; n < NN; ++n)
    h[n] = fmaxf(fmaf(xb[2*n], we0, fmaf(xb[2*n+1], we1, be)), 0.f);
  #pragma unroll
  for (int n = 0; n < NN; ++n){
    float a = 0.f;
    #pragma unroll
    for (int j = 0; j < 4; ++j) if (j < CNT[n]) a += h[NBR[n][j]];
    s1[n] = fmaf(INVDEG[n], a, h[n]);
  }
}

// wave-shuffle BN-stat reduction, atomics spread over slots by caller.
__device__ inline void reduce_stats(float* sA, float* qA,
                                    float* __restrict__ gSum, float* __restrict__ gSq){
  int t = threadIdx.x;
  #pragma unroll
  for (int n = 0; n < NN; ++n){
    float s = sA[n], q = qA[n];
    #pragma unroll
    for (int off = 32; off > 0; off >>= 1){
      s += __shfl_down(s, off, 64);
      q += __shfl_down(q, off, 64);
    }
    sA[n] = s; qA[n] = q;
  }
  __shared__ float shS[NN], shQ[NN];
  if (t < NN){ shS[t] = 0.f; shQ[t] = 0.f; }
  __syncthreads();
  if ((t & 63) == 0){
    #pragma unroll
    for (int n = 0; n < NN; ++n){ atomicAdd(&shS[n], sA[n]); atomicAdd(&shQ[n], qA[n]); }
  }
  __syncthreads();
  if (t < NN){ atomicAdd(&gSum[t], shS[t]); atomicAdd(&gSq[t], shQ[t]); }
}

// ---- MFMA-based BN stats over a 272x64 bf16 LDS tile (XOR-swizzled rows) ----
__device__ inline void mfma_stats(const char* hsm, float* sred, int t,
                                  float* __restrict__ gSum, float* __restrict__ gSq){
  const int w4 = t >> 6, lo = t & 15, q = (t >> 4) & 3;
  bf16x8 one;
  { union { ushort16 u[8]; bf16x8 v; } c;
    #pragma unroll
    for (int i = 0; i < 8; ++i) c.u[i] = 0x3F80;
    one = c.v; }
  #pragma unroll
  for (int i = 0; i < 5; ++i){
    int mt = w4 + i*4;
    if (mt < 17){
      f32x4 d0 = (f32x4)0.f, d1 = (f32x4)0.f;
      #pragma unroll
      for (int s = 0; s < 2; ++s){
        int r = mt*16 + lo;
        bf16x8 a = *(const bf16x8*)(hsm + ((r*128 + s*64 + q*16) ^ ((r & 7) << 4)));
        d0 = MFMA(a, one, d0);
        d1 = MFMA(a, a, d1);
      }
      if (lo == 0){
        #pragma unroll
        for (int j = 0; j < 4; ++j) sred[mt*16 + q*4 + j] = d0[j];
      }
      if ((lo >> 2) == q) sred[272 + mt*16 + lo] = d1[lo & 3];
    }
  }
  __syncthreads();
  if (t < NN){
    float s = 0.f, qq = 0.f;
    #pragma unroll
    for (int bl = 0; bl < 16; ++bl){
      s  += sred[t + 17*bl];
      qq += sred[272 + t + 17*bl];
    }
    atomicAdd(&gSum[t], s);
    atomicAdd(&gSq[t], qq);
  }
}

// ---- pre-cast + weight layout prep ----
// W1F: LANE-LINEAR fragment layout: elem g -> fb=g>>9 (=ks*16+nt), r=g&511,
//   lane=r>>3, j=r&7;  n = nt*16 + (lane&15), k = ks*32 + (lane>>4)*8 + j.
// W2T[e][k] = W_p2[k][e].  WGT: W1hi,W1lo,W2hi,W2lo transposed gc weights.
__global__ __launch_bounds__(256) void k_prep(const float* __restrict__ Wp1,
                                              const float* __restrict__ Wp2,
                                              const float* __restrict__ Wg1,
                                              const float* __restrict__ Wg2,
                                              ushort16* __restrict__ W1F,
                                              ushort16* __restrict__ W2T,
                                              ushort16* __restrict__ WGT,
                                              float* __restrict__ colsum2){
  int g = blockIdx.x * 256 + threadIdx.x;
  if (g < 278528){
    int fb = g >> 9, r = g & 511;
    int ks = fb >> 4, nt = fb & 15;
    int lane = r >> 3, j = r & 7;
    int n = nt*16 + (lane & 15), k = ks*32 + (lane >> 4)*8 + j;
    W1F[g] = f2bfu(Wp1[(size_t)k*256 + n]);
  } else if (g < 311296){
    int h = g - 278528;
    int e = h >> 8, k = h & 255;
    W2T[h] = f2bfu(Wp2[(size_t)k*128 + e]);
  } else if (g < 327680){
    int h = g - 311296;
    int sel = h >> 12;                 // 0:W1hi 1:W1lo 2:W2hi 3:W2lo
    int idx = h & 4095;
    int e = idx >> 6, d = idx & 63;
    const float* Wsrc = (sel < 2) ? Wg1 : Wg2;
    float v = Wsrc[d*64 + e];
    __hip_bfloat16 hi = __float2bfloat16(v);
    if (sel & 1){
      float rem = v - __bfloat162float(hi);
      WGT[h] = f2bfu(rem);
    } else {
      WGT[h] = f2bfu(v);
    }
  } else {
    int e = g - 327680;
    if (e < 64){
      float cs = 0.f;
      for (int d = 0; d < 64; ++d){
        float v = Wg2[d*64 + e];
        float hi = __bfloat162float(__float2bfloat16(v));
        float lo = __bfloat162float(__float2bfloat16(v - hi));
        cs += hi + lo;
      }
      colsum2[e] = cs;
    }
  }
}

// SH[n*64+e] = shift2[n]*colsum2[e] + b_gc2[e]
__global__ void k_sh(const float* __restrict__ shift2, const float* __restrict__ colsum2,
                     const float* __restrict__ bg2, float* __restrict__ SH){
  int n = blockIdx.x, e = threadIdx.x;
  SH[n*64 + e] = fmaf(shift2[n], colsum2[e], bg2[e]);
}

// ---- pass 1: BN1 statistics over s1 = enc+agg (register + shuffle) ----
__global__ __launch_bounds__(256,4) void k_stats1(const float* __restrict__ x,
    const float* __restrict__ W_enc, const float* __restrict__ b_enc,
    float* __restrict__ gSum, float* __restrict__ gSq){
  __shared__ __align__(16) float xs[1088];     // 32 rows x 34 = 272 float4
  int t = threadIdx.x, e = t & 63, lb = t >> 6;
  float we0 = W_enc[e], we1 = W_enc[64 + e], be = b_enc[e];
  const float4* xg = (const float4*)(x + (size_t)blockIdx.x*1088);
  ((float4*)xs)[t] = xg[t];
  if (t < 16) ((float4*)xs)[256 + t] = xg[256 + t];   // tail: 272 float4 > 256 threads
  float sA[NN], qA[NN];
  #pragma unroll
  for (int n = 0; n < NN; ++n){ sA[n] = 0.f; qA[n] = 0.f; }
  __syncthreads();
  for (int it = 0; it < 8; ++it){
    float s1[NN];
    enc_agg(xs + (it*4 + lb)*34, we0, we1, be, s1);
    #pragma unroll
    for (int n = 0; n < NN; ++n){ sA[n] += s1[n]; qA[n] += s1[n]*s1[n]; }
  }
  int slot = (blockIdx.x & 31) * 32;
  reduce_stats(sA, qA, gSum + slot, gSq + slot);
}

__global__ void k_finalize(const float* __restrict__ gSum, const float* __restrict__ gSq,
                           const float* __restrict__ gamma, const float* __restrict__ beta,
                           float* __restrict__ scale, float* __restrict__ shift){
  int n = threadIdx.x;
  if (n < NN){
    float s = 0.f, qq = 0.f;
    for (int sl = 0; sl < 32; ++sl){ s += gSum[sl*32 + n]; qq += gSq[sl*32 + n]; }
    const float invC = 1.0f / (float)((size_t)B_TOTAL * 64);
    float mean = s * invC;
    float var  = qq * invC - mean*mean;
    float istd = rsqrtf(var + 1e-5f);
    float sc   = gamma[n] * istd;
    scale[n] = sc;
    shift[n] = fmaf(-mean, sc, beta[n]);
  }
}

// ---- pass 2: enc+agg, BN1 -> hn(bf16 LDS), MFMA gc1, relu, agg -> S + BN2 stats ----
__global__ __launch_bounds__(256,4) void k_gc1(const float* __restrict__ x,
    const float* __restrict__ W_enc, const float* __restrict__ b_enc,
    const float* __restrict__ bg,
    const float* __restrict__ scale, const float* __restrict__ shift,
    const __hip_bfloat16* __restrict__ Whi, const __hip_bfloat16* __restrict__ Wlo,
    __hip_bfloat16* __restrict__ S, float* __restrict__ gSum, float* __restrict__ gSq){
  __shared__ __align__(16) char hsm[272*128];
  __shared__ float sred[544];
  __shared__ __align__(16) float xs[544];      // 16 rows x 34 = 136 float4
  __shared__ float sc_s[NN], sf_s[NN];
  const int t = threadIdx.x, e = t & 63, lb = t >> 6;
  const int w4 = t >> 6, lo = t & 15, q = (t >> 4) & 3;
  if (t < NN){ sc_s[t] = scale[t]; sf_s[t] = shift[t]; }
  if (t < 136) ((float4*)xs)[t] = ((const float4*)(x + (size_t)blockIdx.x*544))[t];
  float we0 = W_enc[e], we1 = W_enc[64 + e], be = b_enc[e];
  __syncthreads();

  // phase 1: enc + agg + BN1-apply -> hn bf16 LDS
  for (int it = 0; it < 4; ++it){
    int bl = it*4 + lb;
    float s1[NN];
    enc_agg(xs + bl*34, we0, we1, be, s1);
    #pragma unroll
    for (int n = 0; n < NN; ++n){
      int row = bl*17 + n;
      int byt = (row*128 + 2*e) ^ ((row & 7) << 4);
      *(__hip_bfloat16*)(hsm + byt) = __float2bfloat16(fmaf(s1[n], sc_s[n], sf_s[n]));
    }
  }
  __syncthreads();

  // phase 2: h2 = hn @ (Whi + Wlo)
  const char* WhiB = (const char*)Whi;
  const char* WloB = (const char*)Wlo;
  f32x4 acc[5][4];
  #pragma unroll
  for (int i = 0; i < 5; ++i)
    #pragma unroll
    for (int et = 0; et < 4; ++et) acc[i][et] = (f32x4)0.f;
  #pragma unroll
  for (int et = 0; et < 4; ++et){
    int col = et*16 + lo;
    bf16x8 wh0 = *(const bf16x8*)(WhiB + col*128 +      q*16);
    bf16x8 wh1 = *(const bf16x8*)(WhiB + col*128 + 64 + q*16);
    bf16x8 wl0 = *(const bf16x8*)(WloB + col*128 +      q*16);
    bf16x8 wl1 = *(const bf16x8*)(WloB + col*128 + 64 + q*16);
    #pragma unroll
    for (int i = 0; i < 5; ++i){
      int mt = w4 + i*4;
      if (mt < 17){
        int r = mt*16 + lo;
        int base = r*128, sw = (r & 7) << 4;
        bf16x8 a0 = *(const bf16x8*)(hsm + ((base +      q*16) ^ sw));
        bf16x8 a1 = *(const bf16x8*)(hsm + ((base + 64 + q*16) ^ sw));
        acc[i][et] = MFMA(a0, wh0, acc[i][et]);
        acc[i][et] = MFMA(a1, wh1, acc[i][et]);
        acc[i][et] = MFMA(a0, wl0, acc[i][et]);
        acc[i][et] = MFMA(a1, wl1, acc[i][et]);
      }
    }
  }
  float bgv[4];
  #pragma unroll
  for (int et = 0; et < 4; ++et) bgv[et] = bg[et*16 + lo];
  __syncthreads();

  // writeback: h2 = relu(acc + bias) -> reuse hsm
  #pragma unroll
  for (int i = 0; i < 5; ++i){
    int mt = w4 + i*4;
    if (mt < 17){
      #pragma unroll
      for (int et = 0; et < 4; ++et){
        #pragma unroll
        for (int j = 0; j < 4; ++j){
          int row = mt*16 + q*4 + j;
          float h2 = fmaxf(acc[i][et][j] + bgv[et], 0.f);
          int byt = (row*128 + (et*16 + lo)*2) ^ ((row & 7) << 4);
          *(__hip_bfloat16*)(hsm + byt) = __float2bfloat16(h2);
        }
      }
    }
  }
  __syncthreads();

  // phase 3: aggregate -> s2, write bf16 in place
  for (int it = 0; it < 4; ++it){
    int bl = it*4 + lb;
    int row0 = bl*17;
    float h2v[NN];
    #pragma unroll
    for (int n = 0; n < NN; ++n){
      int row = row0 + n;
      h2v[n] = __bfloat162float(*(const __hip_bfloat16*)(hsm + ((row*128 + 2*e) ^ ((row & 7) << 4))));
    }
    #pragma unroll
    for (int n = 0; n < NN; ++n){
      float agg = 0.f;
      #pragma unroll
      for (int j = 0; j < 4; ++j) if (j < CNT[n]) agg += h2v[NBR[n][j]];
      float s2 = fmaf(INVDEG[n], agg, h2v[n]);
      int row = row0 + n;
      *(__hip_bfloat16*)(hsm + ((row*128 + 2*e) ^ ((row & 7) << 4))) = __float2bfloat16(s2);
    }
  }
  __syncthreads();

  // BN2 stats via MFMA (slot-spread atomics)
  int slot = (blockIdx.x & 31) * 32;
  mfma_stats(hsm, sred, t, gSum + slot, gSq + slot);

  // coalesced copy of the 272x128B tile -> S
  const size_t gbase = (size_t)blockIdx.x * 34816;
  char* Sc = (char*)S;
  #pragma unroll
  for (int k = 0; k < 9; ++k){
    int g = t + k*256;
    if (g < 2176){
      int row = g >> 3;
      uint4 v = *(const uint4*)(hsm + ((g*16) ^ ((row & 7) << 4)));
      *(uint4*)(Sc + gbase + (size_t)g*16) = v;
    }
  }
}

// ---- pass 3: fused gc2 + pooled MLP + L2 normalize (LEAN: 64 rows/block) ----
// 1024 blocks x 64 rows, 4 waves. Register budget halved vs r5 (acc[8][2]=64,
// br[2], g[4], pf[2], wf 1-at-a-time) -> no scratch spills. LDS 48KB ->
// 3 blocks/CU (12 waves/CU). W staged dbuf from lane-linear W1F (conflict-free);
// P dbuf 2x8KB produced per node by operand-swapped gc2 MFMA (BN2 folded).
// z (64x512B, 32KB) overlays dead P+W0 after the main loop.
__global__ __launch_bounds__(256,3) void k_back(
    const __hip_bfloat16* __restrict__ S,
    const ushort16* __restrict__ W1F, const float* __restrict__ b_p1,
    const ushort16* __restrict__ W2T, const float* __restrict__ b_p2,
    const __hip_bfloat16* __restrict__ WG2,   // hi; lo at +4096 elems
    const float* __restrict__ scale2, const float* __restrict__ SH,
    float* __restrict__ out){
  __shared__ __align__(16) char smem[49152];
  const int t = threadIdx.x;
  const int L = t & 63, w = t >> 6;
  const int lo = L & 15, q = L >> 4;
  const int wspec = w >> 1, wrow = w & 1;
  const size_t b0 = (size_t)blockIdx.x * 64;
  const char* Sb  = (const char*)S;
  const char* W1b = (const char*)W1F;
  const char* W2b = (const char*)W2T;
  const char* Wgb = (const char*)WG2;

  f32x4 acc[8][2];
  #pragma unroll
  for (int nt = 0; nt < 8; ++nt){ acc[nt][0] = (f32x4)0.f; acc[nt][1] = (f32x4)0.f; }

  // ---- W staging (register path, double-buffered), 16KB per k-step ----
  uint4 wr[4];
  auto loadW = [&](int ks){
    const char* src = W1b + (size_t)ks*16384 + t*16;
    #pragma unroll
    for (int i = 0; i < 4; ++i) wr[i] = *(const uint4*)(src + i*4096);
  };
  auto writeW = [&](int buf){
    char* Wb = smem + 16384 + buf*16384 + t*16;
    #pragma unroll
    for (int i = 0; i < 4; ++i) *(uint4*)(Wb + i*4096) = wr[i];
  };

  // ---- S staging: each wave loads its 16 rows (k 0..63 of node n) ----
  uint4 br[2];
  auto loadS2 = [&](int n){
    const char* base = Sb + (b0 + (size_t)(w*16 + lo))*2176 + n*128 + q*16;
    br[0] = *(const uint4*)(base);
    br[1] = *(const uint4*)(base + 64);
  };
  // gc2 for node n: each wave produces P rows w*16..w*16+15 (64 e-cols).
  auto gc2w = [&](int n){
    char* Pb = smem + (n & 1)*8192;
    float sc = scale2[n];
    f32x4 g[4];
    #pragma unroll
    for (int et = 0; et < 4; ++et) g[et] = (f32x4)0.f;
    union { uint4 u; bf16x8 v; } c0, c1;
    c0.u = br[0]; c1.u = br[1];
    #pragma unroll
    for (int et = 0; et < 4; ++et){
      const char* A = Wgb + (et*16 + lo)*128 + q*16;
      bf16x8 ah0 = *(const bf16x8*)(A);
      bf16x8 ah1 = *(const bf16x8*)(A + 64);
      bf16x8 al0 = *(const bf16x8*)(A + 8192);
      bf16x8 al1 = *(const bf16x8*)(A + 8192 + 64);
      g[et] = MFMA(ah0, c0.v, g[et]);
      g[et] = MFMA(al0, c0.v, g[et]);
      g[et] = MFMA(ah1, c1.v, g[et]);
      g[et] = MFMA(al1, c1.v, g[et]);
    }
    int b = w*16 + lo;
    #pragma unroll
    for (int et = 0; et < 4; ++et){
      float4 sh4 = *(const float4*)&SH[n*64 + et*16 + q*4];
      float v0 = fmaxf(fmaf(sc, g[et].x, sh4.x), 0.f);
      float v1 = fmaxf(fmaf(sc, g[et].y, sh4.y), 0.f);
      float v2 = fmaxf(fmaf(sc, g[et].z, sh4.z), 0.f);
      float v3 = fmaxf(fmaf(sc, g[et].w, sh4.w), 0.f);
      uint32 u0 = (uint32)f2bfu(v0) | ((uint32)f2bfu(v1) << 16);
      uint32 u1 = (uint32)f2bfu(v2) | ((uint32)f2bfu(v3) << 16);
      int byt = (b*128 + (et*16 + q*4)*2) ^ ((b & 7) << 4);
      *(uint2*)(Pb + byt) = make_uint2(u0, u1);
    }
  };

  loadS2(0);
  gc2w(0);
  loadW(0);
  writeW(0);
  __syncthreads();

  #pragma unroll 1
  for (int ks = 0; ks < 34; ++ks){
    const int n = ks >> 1, half = ks & 1;
    if (ks < 33) loadW(ks + 1);
    if (half == 0 && n < 16) loadS2(n + 1);
    const char* Pb = smem + (n & 1)*8192;
    const char* Wb = smem + 16384 + (ks & 1)*16384;
    bf16x8 pf[2];
    #pragma unroll
    for (int bt = 0; bt < 2; ++bt){
      int r = wrow*32 + bt*16 + lo;
      pf[bt] = *(const bf16x8*)(Pb + ((r*128 + half*64 + q*16) ^ ((r & 7) << 4)));
    }
    #pragma unroll
    for (int nt = 0; nt < 8; ++nt){
      bf16x8 wf = *(const bf16x8*)(Wb + (wspec*8 + nt)*1024 + L*16);
      acc[nt][0] = MFMA(wf, pf[0], acc[nt][0]);
      acc[nt][1] = MFMA(wf, pf[1], acc[nt][1]);
    }
    if (half == 1 && n < 16) gc2w(n + 1);
    if (ks < 33) writeW((ks & 1) ^ 1);
    __syncthreads();
  }

  // ---- z: all 4 waves write their acc (disjoint rows x cols) ----
  #pragma unroll
  for (int nt = 0; nt < 8; ++nt){
    float4 bias = *(const float4*)&b_p1[(wspec*8 + nt)*16 + q*4];
    #pragma unroll
    for (int bt = 0; bt < 2; ++bt){
      int r = wrow*32 + bt*16 + lo;
      f32x4 v = acc[nt][bt];
      float z0 = fmaxf(v.x + bias.x, 0.f), z1 = fmaxf(v.y + bias.y, 0.f);
      float z2 = fmaxf(v.z + bias.z, 0.f), z3 = fmaxf(v.w + bias.w, 0.f);
      uint32 lo32 = (uint32)f2bfu(z0) | ((uint32)f2bfu(z1) << 16);
      uint32 hi32 = (uint32)f2bfu(z2) | ((uint32)f2bfu(z3) << 16);
      int nbyte = ((wspec*8 + nt)*16 + q*4)*2;
      int addr = r*512 + (nbyte ^ ((r & 7) << 4));
      *(uint2*)(smem + addr) = make_uint2(lo32, hi32);
    }
  }
  __syncthreads();

  // emb^T = W2T @ z^T ; each wave handles rows w*16..w*16+15
  f32x4 acc2[8];
  #pragma unroll
  for (int et = 0; et < 8; ++et) acc2[et] = (f32x4)0.f;
  #pragma unroll
  for (int ks2 = 0; ks2 < 8; ++ks2){
    int r = w*16 + lo;
    bf16x8 zf = *(const bf16x8*)(smem + r*512 + ((ks2*64 + q*16) ^ ((r & 7) << 4)));
    #pragma unroll
    for (int et = 0; et < 8; ++et){
      bf16x8 wf2 = *(const bf16x8*)(W2b + (et*16 + lo)*512 + ks2*64 + q*16);
      acc2[et] = MFMA(wf2, zf, acc2[et]);
    }
  }

  // + b_p2, L2-normalize rows, store
  float4 vv[8];
  float ss = 0.f;
  #pragma unroll
  for (int et = 0; et < 8; ++et){
    float4 bias = *(const float4*)&b_p2[et*16 + q*4];
    vv[et].x = acc2[et].x + bias.x; vv[et].y = acc2[et].y + bias.y;
    vv[et].z = acc2[et].z + bias.z; vv[et].w = acc2[et].w + bias.w;
    ss += vv[et].x*vv[et].x + vv[et].y*vv[et].y + vv[et].z*vv[et].z + vv[et].w*vv[et].w;
  }
  ss += __shfl_xor(ss, 16, 64);
  ss += __shfl_xor(ss, 32, 64);
  float inv = 1.0f / fmaxf(sqrtf(ss), 1e-12f);
  float* op = out + (b0 + w*16 + lo)*128;
  #pragma unroll
  for (int et = 0; et < 8; ++et){
    float4 o; o.x = vv[et].x*inv; o.y = vv[et].y*inv; o.z = vv[et].z*inv; o.w = vv[et].w*inv;
    *(float4*)(op + et*16 + q*4) = o;
  }
}

extern "C" void kernel_launch(void* const* d_in, const int* in_sizes, int n_in,
                              void* d_out, int out_size, void* d_ws, size_t ws_size,
                              hipStream_t stream) {
  const float* x     = (const float*)d_in[0];
  const float* W_enc = (const float*)d_in[1];
  const float* b_enc = (const float*)d_in[2];
  const float* W_gc1 = (const float*)d_in[3];
  const float* b_gc1 = (const float*)d_in[4];
  const float* W_gc2 = (const float*)d_in[5];
  const float* b_gc2 = (const float*)d_in[6];
  const float* gamma1= (const float*)d_in[7];
  const float* beta1 = (const float*)d_in[8];
  const float* gamma2= (const float*)d_in[9];
  const float* beta2 = (const float*)d_in[10];
  const float* W_p1  = (const float*)d_in[11];
  const float* b_p1  = (const float*)d_in[12];
  const float* W_p2  = (const float*)d_in[13];
  const float* b_p2  = (const float*)d_in[14];
  float* out = (float*)d_out;

  char* ws = (char*)d_ws;
  __hip_bfloat16* S = (__hip_bfloat16*)ws;
  float*    stats = (float*)(ws + STATS_OFF);
  ushort16* W1F   = (ushort16*)(ws + W1_OFF);
  ushort16* W2T   = (ushort16*)(ws + W2_OFF);
  __hip_bfloat16* WGT = (__hip_bfloat16*)(ws + WGT_OFF);

  (void)hipMemsetAsync(stats, 0, 16384, stream);

  k_prep<<<1281, 256, 0, stream>>>(W_p1, W_p2, W_gc1, W_gc2, W1F, W2T,
                                   (ushort16*)WGT, stats + 4224);
  k_stats1<<<2048, 256, 0, stream>>>(x, W_enc, b_enc, stats + 0, stats + 1024);
  k_finalize<<<1, 32, 0, stream>>>(stats + 0, stats + 1024, gamma1, beta1,
                                   stats + 4096, stats + 4128);
  k_gc1<<<4096, 256, 0, stream>>>(x, W_enc, b_enc, b_gc1,
                                  stats + 4096, stats + 4128,
                                  WGT, WGT + 4096,
                                  S, stats + 2048, stats + 3072);
  k_finalize<<<1, 32, 0, stream>>>(stats + 2048, stats + 3072, gamma2, beta2,
                                   stats + 4160, stats + 4192);
  k_sh<<<17, 64, 0, stream>>>(stats + 4192, stats + 4224, b_gc2, stats + 4288);
  k_back<<<1024, 256, 0, stream>>>(S, W1F, b_p1, W2T, b_p2,
                                   WGT + 8192, stats + 4160, stats + 4288, out);
}

// Round 7
// 368.843 us; speedup vs baseline: 1.3605x; 1.3605x over previous
//
#include <hip/hip_runtime.h>
#include <hip/hip_bf16.h>

typedef unsigned int  uint32;
typedef unsigned short ushort16;

#define B_TOTAL 65536
#define NN 17

typedef __bf16 bf16x8 __attribute__((ext_vector_type(8)));
typedef float  f32x4  __attribute__((ext_vector_type(4)));

// ---- fixed normalized adjacency (from EDGES in the reference) ----
static constexpr int   CNT[NN]    = {2,0,0,0,0,4,4,2,2,1,1,3,3,2,2,1,1};
static constexpr int   NBR[NN][4] = {
  {5,6,0,0},{0,0,0,0},{0,0,0,0},{0,0,0,0},{0,0,0,0},
  {7,6,11,0},{8,5,12,0},{5,9,0,0},{6,10,0,0},{7,0,0,0},{8,0,0,0},
  {5,12,13,0},{6,11,14,0},{11,15,0,0},{12,16,0,0},{13,0,0,0},{14,0,0,0}};
static constexpr float INVDEG[NN] = {0.5f,0.f,0.f,0.f,0.f,0.25f,0.25f,0.5f,0.5f,1.f,1.f,
  0.33333333333333333f,0.33333333333333333f,0.5f,0.5f,1.f,1.f};

// ---- workspace layout (bytes) ----
#define S_BYTES   ((size_t)B_TOTAL * 1088 * 2)
#define STATS_OFF S_BYTES
#define W1_OFF    (STATS_OFF + 40960)
#define W2_OFF    (W1_OFF + (size_t)278528*2)
#define WGT_OFF   (W2_OFF + (size_t)65536)   // 4 x 4096 bf16: W1hi, W1lo, W2hi, W2lo

// stats float offsets:
//   0     sum1[32 slots][32]      1024  sq1[32][32]
//   2048  sum2[32][32]            3072  sq2[32][32]
//   4096  sc1[32]  4128 sf1[32]   4160  sc2[32]  4192 sf2[32]
//   4224  colsum2[64]             4288  SH[1088]

__device__ inline ushort16 f2bfu(float f){
  union { __hip_bfloat16 h; ushort16 u; } c; c.h = __float2bfloat16(f); return c.u;
}

__device__ inline f32x4 MFMA(bf16x8 a, bf16x8 b, f32x4 c){
  return __builtin_amdgcn_mfma_f32_16x16x32_bf16(a, b, c, 0, 0, 0);
}

// encoder + normalized-adjacency aggregate for one batch row, one feature dim e.
__device__ inline void enc_agg(const float* __restrict__ xb,
                               float we0, float we1, float be, float* s1){
  float h[NN];
  #pragma unroll
  for (int n = 0; n < NN; ++n)
    h[n] = fmaxf(fmaf(xb[2*n], we0, fmaf(xb[2*n+1], we1, be)), 0.f);
  #pragma unroll
  for (int n = 0; n < NN; ++n){
    float a = 0.f;
    #pragma unroll
    for (int j = 0; j < 4; ++j) if (j < CNT[n]) a += h[NBR[n][j]];
    s1[n] = fmaf(INVDEG[n], a, h[n]);
  }
}

// wave-shuffle BN-stat reduction, atomics spread over slots by caller.
__device__ inline void reduce_stats(float* sA, float* qA,
                                    float* __restrict__ gSum, float* __restrict__ gSq){
  int t = threadIdx.x;
  #pragma unroll
  for (int n = 0; n < NN; ++n){
    float s = sA[n], q = qA[n];
    #pragma unroll
    for (int off = 32; off > 0; off >>= 1){
      s += __shfl_down(s, off, 64);
      q += __shfl_down(q, off, 64);
    }
    sA[n] = s; qA[n] = q;
  }
  __shared__ float shS[NN], shQ[NN];
  if (t < NN){ shS[t] = 0.f; shQ[t] = 0.f; }
  __syncthreads();
  if ((t & 63) == 0){
    #pragma unroll
    for (int n = 0; n < NN; ++n){ atomicAdd(&shS[n], sA[n]); atomicAdd(&shQ[n], qA[n]); }
  }
  __syncthreads();
  if (t < NN){ atomicAdd(&gSum[t], shS[t]); atomicAdd(&gSq[t], shQ[t]); }
}

// ---- MFMA-based BN stats over a 272x64 bf16 LDS tile (XOR-swizzled rows) ----
__device__ inline void mfma_stats(const char* hsm, float* sred, int t,
                                  float* __restrict__ gSum, float* __restrict__ gSq){
  const int w4 = t >> 6, lo = t & 15, q = (t >> 4) & 3;
  bf16x8 one;
  { union { ushort16 u[8]; bf16x8 v; } c;
    #pragma unroll
    for (int i = 0; i < 8; ++i) c.u[i] = 0x3F80;
    one = c.v; }
  #pragma unroll
  for (int i = 0; i < 5; ++i){
    int mt = w4 + i*4;
    if (mt < 17){
      f32x4 d0 = (f32x4)0.f, d1 = (f32x4)0.f;
      #pragma unroll
      for (int s = 0; s < 2; ++s){
        int r = mt*16 + lo;
        bf16x8 a = *(const bf16x8*)(hsm + ((r*128 + s*64 + q*16) ^ ((r & 7) << 4)));
        d0 = MFMA(a, one, d0);
        d1 = MFMA(a, a, d1);
      }
      if (lo == 0){
        #pragma unroll
        for (int j = 0; j < 4; ++j) sred[mt*16 + q*4 + j] = d0[j];
      }
      if ((lo >> 2) == q) sred[272 + mt*16 + lo] = d1[lo & 3];
    }
  }
  __syncthreads();
  if (t < NN){
    float s = 0.f, qq = 0.f;
    #pragma unroll
    for (int bl = 0; bl < 16; ++bl){
      s  += sred[t + 17*bl];
      qq += sred[272 + t + 17*bl];
    }
    atomicAdd(&gSum[t], s);
    atomicAdd(&gSq[t], qq);
  }
}

// ---- pre-cast + weight layout prep ----
// W1F: LANE-LINEAR fragment layout: elem g -> fb=g>>9 (=ks*16+nt), r=g&511,
//   lane=r>>3, j=r&7;  n = nt*16 + (lane&15), k = ks*32 + (lane>>4)*8 + j.
// W2T[e][k] = W_p2[k][e].  WGT: W1hi,W1lo,W2hi,W2lo transposed gc weights.
__global__ __launch_bounds__(256) void k_prep(const float* __restrict__ Wp1,
                                              const float* __restrict__ Wp2,
                                              const float* __restrict__ Wg1,
                                              const float* __restrict__ Wg2,
                                              ushort16* __restrict__ W1F,
                                              ushort16* __restrict__ W2T,
                                              ushort16* __restrict__ WGT,
                                              float* __restrict__ colsum2){
  int g = blockIdx.x * 256 + threadIdx.x;
  if (g < 278528){
    int fb = g >> 9, r = g & 511;
    int ks = fb >> 4, nt = fb & 15;
    int lane = r >> 3, j = r & 7;
    int n = nt*16 + (lane & 15), k = ks*32 + (lane >> 4)*8 + j;
    W1F[g] = f2bfu(Wp1[(size_t)k*256 + n]);
  } else if (g < 311296){
    int h = g - 278528;
    int e = h >> 8, k = h & 255;
    W2T[h] = f2bfu(Wp2[(size_t)k*128 + e]);
  } else if (g < 327680){
    int h = g - 311296;
    int sel = h >> 12;                 // 0:W1hi 1:W1lo 2:W2hi 3:W2lo
    int idx = h & 4095;
    int e = idx >> 6, d = idx & 63;
    const float* Wsrc = (sel < 2) ? Wg1 : Wg2;
    float v = Wsrc[d*64 + e];
    __hip_bfloat16 hi = __float2bfloat16(v);
    if (sel & 1){
      float rem = v - __bfloat162float(hi);
      WGT[h] = f2bfu(rem);
    } else {
      WGT[h] = f2bfu(v);
    }
  } else {
    int e = g - 327680;
    if (e < 64){
      float cs = 0.f;
      for (int d = 0; d < 64; ++d){
        float v = Wg2[d*64 + e];
        float hi = __bfloat162float(__float2bfloat16(v));
        float lo = __bfloat162float(__float2bfloat16(v - hi));
        cs += hi + lo;
      }
      colsum2[e] = cs;
    }
  }
}

// SH[n*64+e] = shift2[n]*colsum2[e] + b_gc2[e]
__global__ void k_sh(const float* __restrict__ shift2, const float* __restrict__ colsum2,
                     const float* __restrict__ bg2, float* __restrict__ SH){
  int n = blockIdx.x, e = threadIdx.x;
  SH[n*64 + e] = fmaf(shift2[n], colsum2[e], bg2[e]);
}

// ---- pass 1: BN1 statistics over s1 = enc+agg (register + shuffle) ----
__global__ __launch_bounds__(256,4) void k_stats1(const float* __restrict__ x,
    const float* __restrict__ W_enc, const float* __restrict__ b_enc,
    float* __restrict__ gSum, float* __restrict__ gSq){
  __shared__ __align__(16) float xs[1088];     // 32 rows x 34 = 272 float4
  int t = threadIdx.x, e = t & 63, lb = t >> 6;
  float we0 = W_enc[e], we1 = W_enc[64 + e], be = b_enc[e];
  const float4* xg = (const float4*)(x + (size_t)blockIdx.x*1088);
  ((float4*)xs)[t] = xg[t];
  if (t < 16) ((float4*)xs)[256 + t] = xg[256 + t];   // tail: 272 float4 > 256 threads
  float sA[NN], qA[NN];
  #pragma unroll
  for (int n = 0; n < NN; ++n){ sA[n] = 0.f; qA[n] = 0.f; }
  __syncthreads();
  for (int it = 0; it < 8; ++it){
    float s1[NN];
    enc_agg(xs + (it*4 + lb)*34, we0, we1, be, s1);
    #pragma unroll
    for (int n = 0; n < NN; ++n){ sA[n] += s1[n]; qA[n] += s1[n]*s1[n]; }
  }
  int slot = (blockIdx.x & 31) * 32;
  reduce_stats(sA, qA, gSum + slot, gSq + slot);
}

__global__ void k_finalize(const float* __restrict__ gSum, const float* __restrict__ gSq,
                           const float* __restrict__ gamma, const float* __restrict__ beta,
                           float* __restrict__ scale, float* __restrict__ shift){
  int n = threadIdx.x;
  if (n < NN){
    float s = 0.f, qq = 0.f;
    for (int sl = 0; sl < 32; ++sl){ s += gSum[sl*32 + n]; qq += gSq[sl*32 + n]; }
    const float invC = 1.0f / (float)((size_t)B_TOTAL * 64);
    float mean = s * invC;
    float var  = qq * invC - mean*mean;
    float istd = rsqrtf(var + 1e-5f);
    float sc   = gamma[n] * istd;
    scale[n] = sc;
    shift[n] = fmaf(-mean, sc, beta[n]);
  }
}

// ---- pass 2: enc+agg, BN1 -> hn(bf16 LDS), MFMA gc1, relu, agg -> S + BN2 stats ----
__global__ __launch_bounds__(256,4) void k_gc1(const float* __restrict__ x,
    const float* __restrict__ W_enc, const float* __restrict__ b_enc,
    const float* __restrict__ bg,
    const float* __restrict__ scale, const float* __restrict__ shift,
    const __hip_bfloat16* __restrict__ Whi, const __hip_bfloat16* __restrict__ Wlo,
    __hip_bfloat16* __restrict__ S, float* __restrict__ gSum, float* __restrict__ gSq){
  __shared__ __align__(16) char hsm[272*128];
  __shared__ float sred[544];
  __shared__ __align__(16) float xs[544];      // 16 rows x 34 = 136 float4
  __shared__ float sc_s[NN], sf_s[NN];
  const int t = threadIdx.x, e = t & 63, lb = t >> 6;
  const int w4 = t >> 6, lo = t & 15, q = (t >> 4) & 3;
  if (t < NN){ sc_s[t] = scale[t]; sf_s[t] = shift[t]; }
  if (t < 136) ((float4*)xs)[t] = ((const float4*)(x + (size_t)blockIdx.x*544))[t];
  float we0 = W_enc[e], we1 = W_enc[64 + e], be = b_enc[e];
  __syncthreads();

  // phase 1: enc + agg + BN1-apply -> hn bf16 LDS
  for (int it = 0; it < 4; ++it){
    int bl = it*4 + lb;
    float s1[NN];
    enc_agg(xs + bl*34, we0, we1, be, s1);
    #pragma unroll
    for (int n = 0; n < NN; ++n){
      int row = bl*17 + n;
      int byt = (row*128 + 2*e) ^ ((row & 7) << 4);
      *(__hip_bfloat16*)(hsm + byt) = __float2bfloat16(fmaf(s1[n], sc_s[n], sf_s[n]));
    }
  }
  __syncthreads();

  // phase 2: h2 = hn @ (Whi + Wlo)
  const char* WhiB = (const char*)Whi;
  const char* WloB = (const char*)Wlo;
  f32x4 acc[5][4];
  #pragma unroll
  for (int i = 0; i < 5; ++i)
    #pragma unroll
    for (int et = 0; et < 4; ++et) acc[i][et] = (f32x4)0.f;
  #pragma unroll
  for (int et = 0; et < 4; ++et){
    int col = et*16 + lo;
    bf16x8 wh0 = *(const bf16x8*)(WhiB + col*128 +      q*16);
    bf16x8 wh1 = *(const bf16x8*)(WhiB + col*128 + 64 + q*16);
    bf16x8 wl0 = *(const bf16x8*)(WloB + col*128 +      q*16);
    bf16x8 wl1 = *(const bf16x8*)(WloB + col*128 + 64 + q*16);
    #pragma unroll
    for (int i = 0; i < 5; ++i){
      int mt = w4 + i*4;
      if (mt < 17){
        int r = mt*16 + lo;
        int base = r*128, sw = (r & 7) << 4;
        bf16x8 a0 = *(const bf16x8*)(hsm + ((base +      q*16) ^ sw));
        bf16x8 a1 = *(const bf16x8*)(hsm + ((base + 64 + q*16) ^ sw));
        acc[i][et] = MFMA(a0, wh0, acc[i][et]);
        acc[i][et] = MFMA(a1, wh1, acc[i][et]);
        acc[i][et] = MFMA(a0, wl0, acc[i][et]);
        acc[i][et] = MFMA(a1, wl1, acc[i][et]);
      }
    }
  }
  float bgv[4];
  #pragma unroll
  for (int et = 0; et < 4; ++et) bgv[et] = bg[et*16 + lo];
  __syncthreads();

  // writeback: h2 = relu(acc + bias) -> reuse hsm
  #pragma unroll
  for (int i = 0; i < 5; ++i){
    int mt = w4 + i*4;
    if (mt < 17){
      #pragma unroll
      for (int et = 0; et < 4; ++et){
        #pragma unroll
        for (int j = 0; j < 4; ++j){
          int row = mt*16 + q*4 + j;
          float h2 = fmaxf(acc[i][et][j] + bgv[et], 0.f);
          int byt = (row*128 + (et*16 + lo)*2) ^ ((row & 7) << 4);
          *(__hip_bfloat16*)(hsm + byt) = __float2bfloat16(h2);
        }
      }
    }
  }
  __syncthreads();

  // phase 3: aggregate -> s2, write bf16 in place
  for (int it = 0; it < 4; ++it){
    int bl = it*4 + lb;
    int row0 = bl*17;
    float h2v[NN];
    #pragma unroll
    for (int n = 0; n < NN; ++n){
      int row = row0 + n;
      h2v[n] = __bfloat162float(*(const __hip_bfloat16*)(hsm + ((row*128 + 2*e) ^ ((row & 7) << 4))));
    }
    #pragma unroll
    for (int n = 0; n < NN; ++n){
      float agg = 0.f;
      #pragma unroll
      for (int j = 0; j < 4; ++j) if (j < CNT[n]) agg += h2v[NBR[n][j]];
      float s2 = fmaf(INVDEG[n], agg, h2v[n]);
      int row = row0 + n;
      *(__hip_bfloat16*)(hsm + ((row*128 + 2*e) ^ ((row & 7) << 4))) = __float2bfloat16(s2);
    }
  }
  __syncthreads();

  // BN2 stats via MFMA (slot-spread atomics)
  int slot = (blockIdx.x & 31) * 32;
  mfma_stats(hsm, sred, t, gSum + slot, gSq + slot);

  // coalesced copy of the 272x128B tile -> S
  const size_t gbase = (size_t)blockIdx.x * 34816;
  char* Sc = (char*)S;
  #pragma unroll
  for (int k = 0; k < 9; ++k){
    int g = t + k*256;
    if (g < 2176){
      int row = g >> 3;
      uint4 v = *(const uint4*)(hsm + ((g*16) ^ ((row & 7) << 4)));
      *(uint4*)(Sc + gbase + (size_t)g*16) = v;
    }
  }
}

// ---- pass 3: fused gc2 + pooled MLP + L2 normalize ----
// r2 geometry (512 blocks x 128 rows, 4 waves, acc[16][2]) + lane-linear W1F
// (conflict-free staging + wf reads) + DEPTH-2 S prefetch (named reg dbuf).
// LDS: [0,32K) P dbuf (2x16K), [32K,64K) W dbuf (2x16K); z overlays all 64K.
__global__ __launch_bounds__(256,2) void k_back(
    const __hip_bfloat16* __restrict__ S,
    const ushort16* __restrict__ W1F, const float* __restrict__ b_p1,
    const ushort16* __restrict__ W2T, const float* __restrict__ b_p2,
    const __hip_bfloat16* __restrict__ WG2,   // hi; lo at +4096 elems
    const float* __restrict__ scale2, const float* __restrict__ SH,
    float* __restrict__ out){
  __shared__ __align__(16) char smem[65536];
  const int t = threadIdx.x;
  const int L = t & 63, w = t >> 6;
  const int lo = L & 15, q = L >> 4;
  const size_t b0 = (size_t)blockIdx.x * 128;
  const char* Sb  = (const char*)S;
  const char* W1b = (const char*)W1F;
  const char* W2b = (const char*)W2T;
  const char* Wgb = (const char*)WG2;

  f32x4 acc[16][2];
  #pragma unroll
  for (int nt = 0; nt < 16; ++nt){ acc[nt][0] = (f32x4)0.f; acc[nt][1] = (f32x4)0.f; }

  // ---- W staging: lane-linear chunks, register dbuf path ----
  uint4 wr[4];
  auto loadW = [&](int ks){
    const char* src = W1b + (size_t)ks*16384 + t*16;
    #pragma unroll
    for (int i = 0; i < 4; ++i) wr[i] = *(const uint4*)(src + i*4096);
  };
  auto writeW = [&](int buf){
    char* Wb = smem + 32768 + buf*16384 + t*16;
    #pragma unroll
    for (int i = 0; i < 4; ++i) *(uint4*)(Wb + i*4096) = wr[i];
  };

  // ---- S prefetch, depth 2: named register double-buffer (A: even n, B: odd n)
  uint4 sa0, sa1, sa2, sa3, sb0, sb1, sb2, sb3;
  auto loadS2A = [&](int n){
    const char* base = Sb + (b0 + (size_t)(w*32 + lo))*2176 + n*128 + q*16;
    sa0 = *(const uint4*)(base);
    sa1 = *(const uint4*)(base + 64);
    sa2 = *(const uint4*)(base + 16*2176);
    sa3 = *(const uint4*)(base + 16*2176 + 64);
  };
  auto loadS2B = [&](int n){
    const char* base = Sb + (b0 + (size_t)(w*32 + lo))*2176 + n*128 + q*16;
    sb0 = *(const uint4*)(base);
    sb1 = *(const uint4*)(base + 64);
    sb2 = *(const uint4*)(base + 16*2176);
    sb3 = *(const uint4*)(base + 16*2176 + 64);
  };
  // gc2 for node n from 4 by-value S fragments; writes P buf (n&1).
  auto gc2core = [&](int n, uint4 r0, uint4 r1, uint4 r2, uint4 r3){
    char* Pb = smem + (n & 1)*16384;
    float sc = scale2[n];
    f32x4 g[2][4];
    #pragma unroll
    for (int bt = 0; bt < 2; ++bt)
      #pragma unroll
      for (int et = 0; et < 4; ++et) g[bt][et] = (f32x4)0.f;
    union { uint4 u; bf16x8 v; } c00, c01, c10, c11;
    c00.u = r0; c01.u = r1; c10.u = r2; c11.u = r3;
    #pragma unroll
    for (int et = 0; et < 4; ++et){
      const char* A = Wgb + (et*16 + lo)*128 + q*16;
      bf16x8 ah0 = *(const bf16x8*)(A);
      bf16x8 ah1 = *(const bf16x8*)(A + 64);
      bf16x8 al0 = *(const bf16x8*)(A + 8192);
      bf16x8 al1 = *(const bf16x8*)(A + 8192 + 64);
      g[0][et] = MFMA(ah0, c00.v, g[0][et]);
      g[0][et] = MFMA(al0, c00.v, g[0][et]);
      g[0][et] = MFMA(ah1, c01.v, g[0][et]);
      g[0][et] = MFMA(al1, c01.v, g[0][et]);
      g[1][et] = MFMA(ah0, c10.v, g[1][et]);
      g[1][et] = MFMA(al0, c10.v, g[1][et]);
      g[1][et] = MFMA(ah1, c11.v, g[1][et]);
      g[1][et] = MFMA(al1, c11.v, g[1][et]);
    }
    #pragma unroll
    for (int et = 0; et < 4; ++et){
      float4 sh4 = *(const float4*)&SH[n*64 + et*16 + q*4];
      #pragma unroll
      for (int bt = 0; bt < 2; ++bt){
        int b = w*32 + bt*16 + lo;
        float v0 = fmaxf(fmaf(sc, g[bt][et].x, sh4.x), 0.f);
        float v1 = fmaxf(fmaf(sc, g[bt][et].y, sh4.y), 0.f);
        float v2 = fmaxf(fmaf(sc, g[bt][et].z, sh4.z), 0.f);
        float v3 = fmaxf(fmaf(sc, g[bt][et].w, sh4.w), 0.f);
        uint32 u0 = (uint32)f2bfu(v0) | ((uint32)f2bfu(v1) << 16);
        uint32 u1 = (uint32)f2bfu(v2) | ((uint32)f2bfu(v3) << 16);
        int byt = (b*128 + (et*16 + q*4)*2) ^ ((b & 7) << 4);
        *(uint2*)(Pb + byt) = make_uint2(u0, u1);
      }
    }
  };

  // prologue: S(0)->A, P(0); S(1)->B; W(0)
  loadS2A(0);
  gc2core(0, sa0, sa1, sa2, sa3);
  loadS2B(1);
  loadW(0);
  writeW(0);
  __syncthreads();

  #pragma unroll 1
  for (int ks = 0; ks < 34; ++ks){
    const int n = ks >> 1, half = ks & 1;
    if (ks < 33) loadW(ks + 1);
    if (half == 0 && n + 2 < 17){            // S(n+2) -> buffer ((n+2)&1) = (n&1)
      if ((n & 1) == 0) loadS2A(n + 2); else loadS2B(n + 2);
    }
    const char* Pb = smem + (n & 1)*16384;
    const char* Wb = smem + 32768 + (ks & 1)*16384;
    int r0 = w*32 + lo, r1 = w*32 + 16 + lo;
    bf16x8 pf0 = *(const bf16x8*)(Pb + ((r0*128 + half*64 + q*16) ^ ((r0 & 7) << 4)));
    bf16x8 pf1 = *(const bf16x8*)(Pb + ((r1*128 + half*64 + q*16) ^ ((r1 & 7) << 4)));
    #pragma unroll
    for (int nt = 0; nt < 16; ++nt){
      bf16x8 wf = *(const bf16x8*)(Wb + nt*1024 + L*16);
      acc[nt][0] = MFMA(wf, pf0, acc[nt][0]);
      acc[nt][1] = MFMA(wf, pf1, acc[nt][1]);
    }
    if (half == 1 && n < 16){                // produce P(n+1) into buf ((n+1)&1)
      if (((n + 1) & 1) == 0) gc2core(n + 1, sa0, sa1, sa2, sa3);
      else                    gc2core(n + 1, sb0, sb1, sb2, sb3);
    }
    if (ks < 33) writeW((ks & 1) ^ 1);
    __syncthreads();
  }

  // epilogue 1: z = relu(z^T + b_p1) -> LDS bf16 [b][256], 8B-granule XOR swizzle
  #pragma unroll
  for (int nt = 0; nt < 16; ++nt){
    float4 bias = *(const float4*)&b_p1[nt*16 + q*4];
    #pragma unroll
    for (int bt = 0; bt < 2; ++bt){
      int b = w*32 + bt*16 + lo;
      f32x4 v = acc[nt][bt];
      float z0 = fmaxf(v.x + bias.x, 0.f), z1 = fmaxf(v.y + bias.y, 0.f);
      float z2 = fmaxf(v.z + bias.z, 0.f), z3 = fmaxf(v.w + bias.w, 0.f);
      uint32 lo32 = (uint32)f2bfu(z0) | ((uint32)f2bfu(z1) << 16);
      uint32 hi32 = (uint32)f2bfu(z2) | ((uint32)f2bfu(z3) << 16);
      int nbyte = (nt*16 + q*4) * 2;
      int addr = b*512 + (nbyte ^ ((b & 7) << 4));
      *(uint2*)(smem + addr) = make_uint2(lo32, hi32);
    }
  }
  __syncthreads();

  // phase 2: emb^T = W2T @ z^T  (K=256, 8 k-steps)
  f32x4 acc2[8][2];
  #pragma unroll
  for (int et = 0; et < 8; ++et){ acc2[et][0] = (f32x4)0.f; acc2[et][1] = (f32x4)0.f; }
  #pragma unroll 1
  for (int ks = 0; ks < 8; ++ks){
    bf16x8 zf0, zf1;
    {
      int b = w*32 + lo;
      int kb = ks*64 + q*16;
      zf0 = *(const bf16x8*)(smem + b*512 + (kb ^ ((b & 7) << 4)));
      b = w*32 + 16 + lo;
      zf1 = *(const bf16x8*)(smem + b*512 + (kb ^ ((b & 7) << 4)));
    }
    #pragma unroll
    for (int et = 0; et < 8; ++et){
      bf16x8 wf = *(const bf16x8*)(W2b + (et*16 + lo)*512 + ks*64 + q*16);
      acc2[et][0] = MFMA(wf, zf0, acc2[et][0]);
      acc2[et][1] = MFMA(wf, zf1, acc2[et][1]);
    }
  }

  // epilogue 2: + b_p2, L2-normalize rows (b), float4 stores
  #pragma unroll
  for (int bt = 0; bt < 2; ++bt){
    int b = w*32 + bt*16 + lo;
    float4 vv[8];
    float ss = 0.f;
    #pragma unroll
    for (int et = 0; et < 8; ++et){
      float4 bias = *(const float4*)&b_p2[et*16 + q*4];
      f32x4 a = bt ? acc2[et][1] : acc2[et][0];
      vv[et].x = a.x + bias.x; vv[et].y = a.y + bias.y;
      vv[et].z = a.z + bias.z; vv[et].w = a.w + bias.w;
      ss += vv[et].x*vv[et].x + vv[et].y*vv[et].y + vv[et].z*vv[et].z + vv[et].w*vv[et].w;
    }
    ss += __shfl_xor(ss, 16, 64);
    ss += __shfl_xor(ss, 32, 64);
    float inv = 1.0f / fmaxf(sqrtf(ss), 1e-12f);
    float* op = out + (b0 + b)*128;
    #pragma unroll
    for (int et = 0; et < 8; ++et){
      float4 o; o.x = vv[et].x*inv; o.y = vv[et].y*inv; o.z = vv[et].z*inv; o.w = vv[et].w*inv;
      *(float4*)(op + et*16 + q*4) = o;
    }
  }
}

extern "C" void kernel_launch(void* const* d_in, const int* in_sizes, int n_in,
                              void* d_out, int out_size, void* d_ws, size_t ws_size,
                              hipStream_t stream) {
  const float* x     = (const float*)d_in[0];
  const float* W_enc = (const float*)d_in[1];
  const float* b_enc = (const float*)d_in[2];
  const float* W_gc1 = (const float*)d_in[3];
  const float* b_gc1 = (const float*)d_in[4];
  const float* W_gc2 = (const float*)d_in[5];
  const float* b_gc2 = (const float*)d_in[6];
  const float* gamma1= (const float*)d_in[7];
  const float* beta1 = (const float*)d_in[8];
  const float* gamma2= (const float*)d_in[9];
  const float* beta2 = (const float*)d_in[10];
  const float* W_p1  = (const float*)d_in[11];
  const float* b_p1  = (const float*)d_in[12];
  const float* W_p2  = (const float*)d_in[13];
  const float* b_p2  = (const float*)d_in[14];
  float* out = (float*)d_out;

  char* ws = (char*)d_ws;
  __hip_bfloat16* S = (__hip_bfloat16*)ws;
  float*    stats = (float*)(ws + STATS_OFF);
  ushort16* W1F   = (ushort16*)(ws + W1_OFF);
  ushort16* W2T   = (ushort16*)(ws + W2_OFF);
  __hip_bfloat16* WGT = (__hip_bfloat16*)(ws + WGT_OFF);

  (void)hipMemsetAsync(stats, 0, 16384, stream);

  k_prep<<<1281, 256, 0, stream>>>(W_p1, W_p2, W_gc1, W_gc2, W1F, W2T,
                                   (ushort16*)WGT, stats + 4224);
  k_stats1<<<2048, 256, 0, stream>>>(x, W_enc, b_enc, stats + 0, stats + 1024);
  k_finalize<<<1, 32, 0, stream>>>(stats + 0, stats + 1024, gamma1, beta1,
                                   stats + 4096, stats + 4128);
  k_gc1<<<4096, 256, 0, stream>>>(x, W_enc, b_enc, b_gc1,
                                  stats + 4096, stats + 4128,
                                  WGT, WGT + 4096,
                                  S, stats + 2048, stats + 3072);
  k_finalize<<<1, 32, 0, stream>>>(stats + 2048, stats + 3072, gamma2, beta2,
                                   stats + 4160, stats + 4192);
  k_sh<<<17, 64, 0, stream>>>(stats + 4192, stats + 4224, b_gc2, stats + 4288);
  k_back<<<512, 256, 0, stream>>>(S, W1F, b_p1, W2T, b_p2,
                                  WGT + 8192, stats + 4160, stats + 4288, out);
}

// Round 8
// 330.879 us; speedup vs baseline: 1.5166x; 1.1147x over previous
//
#include <hip/hip_runtime.h>
#include <hip/hip_bf16.h>

typedef unsigned int  uint32;
typedef unsigned short ushort16;

#define B_TOTAL 65536
#define NN 17

typedef __bf16 bf16x8 __attribute__((ext_vector_type(8)));
typedef float  f32x4  __attribute__((ext_vector_type(4)));

// ---- fixed normalized adjacency (from EDGES in the reference) ----
static constexpr int   CNT[NN]    = {2,0,0,0,0,4,4,2,2,1,1,3,3,2,2,1,1};
static constexpr int   NBR[NN][4] = {
  {5,6,0,0},{0,0,0,0},{0,0,0,0},{0,0,0,0},{0,0,0,0},
  {7,6,11,0},{8,5,12,0},{5,9,0,0},{6,10,0,0},{7,0,0,0},{8,0,0,0},
  {5,12,13,0},{6,11,14,0},{11,15,0,0},{12,16,0,0},{13,0,0,0},{14,0,0,0}};
static constexpr float INVDEG[NN] = {0.5f,0.f,0.f,0.f,0.f,0.25f,0.25f,0.5f,0.5f,1.f,1.f,
  0.33333333333333333f,0.33333333333333333f,0.5f,0.5f,1.f,1.f};

// ---- workspace layout (bytes) ----
#define S_BYTES   ((size_t)B_TOTAL * 1088 * 2)
#define STATS_OFF S_BYTES
#define W1_OFF    (STATS_OFF + 40960)
#define W2_OFF    (W1_OFF + (size_t)278528*2)
#define WGT_OFF   (W2_OFF + (size_t)65536)   // 4 x 4096 bf16: W1hi, W1lo, W2hi, W2lo

// stats float offsets:
//   0     sum1[32 slots][32]      1024  sq1[32][32]
//   2048  sum2[32][32]            3072  sq2[32][32]
//   4096  sc1[32]  4128 sf1[32]   4160  sc2[32]  4192 sf2[32]
//   4224  colsum2[64]             4288  SH[1088]

__device__ inline ushort16 f2bfu(float f){
  union { __hip_bfloat16 h; ushort16 u; } c; c.h = __float2bfloat16(f); return c.u;
}

__device__ inline f32x4 MFMA(bf16x8 a, bf16x8 b, f32x4 c){
  return __builtin_amdgcn_mfma_f32_16x16x32_bf16(a, b, c, 0, 0, 0);
}

// encoder + normalized-adjacency aggregate for one batch row, one feature dim e.
__device__ inline void enc_agg(const float* __restrict__ xb,
                               float we0, float we1, float be, float* s1){
  float h[NN];
  #pragma unroll
  for (int n = 0; n < NN; ++n)
    h[n] = fmaxf(fmaf(xb[2*n], we0, fmaf(xb[2*n+1], we1, be)), 0.f);
  #pragma unroll
  for (int n = 0; n < NN; ++n){
    float a = 0.f;
    #pragma unroll
    for (int j = 0; j < 4; ++j) if (j < CNT[n]) a += h[NBR[n][j]];
    s1[n] = fmaf(INVDEG[n], a, h[n]);
  }
}

// wave-shuffle BN-stat reduction, atomics spread over slots by caller.
__device__ inline void reduce_stats(float* sA, float* qA,
                                    float* __restrict__ gSum, float* __restrict__ gSq){
  int t = threadIdx.x;
  #pragma unroll
  for (int n = 0; n < NN; ++n){
    float s = sA[n], q = qA[n];
    #pragma unroll
    for (int off = 32; off > 0; off >>= 1){
      s += __shfl_down(s, off, 64);
      q += __shfl_down(q, off, 64);
    }
    sA[n] = s; qA[n] = q;
  }
  __shared__ float shS[NN], shQ[NN];
  if (t < NN){ shS[t] = 0.f; shQ[t] = 0.f; }
  __syncthreads();
  if ((t & 63) == 0){
    #pragma unroll
    for (int n = 0; n < NN; ++n){ atomicAdd(&shS[n], sA[n]); atomicAdd(&shQ[n], qA[n]); }
  }
  __syncthreads();
  if (t < NN){ atomicAdd(&gSum[t], shS[t]); atomicAdd(&gSq[t], shQ[t]); }
}

// ---- MFMA-based BN stats over a 272x64 bf16 LDS tile (XOR-swizzled rows) ----
__device__ inline void mfma_stats(const char* hsm, float* sred, int t,
                                  float* __restrict__ gSum, float* __restrict__ gSq){
  const int w4 = t >> 6, lo = t & 15, q = (t >> 4) & 3;
  bf16x8 one;
  { union { ushort16 u[8]; bf16x8 v; } c;
    #pragma unroll
    for (int i = 0; i < 8; ++i) c.u[i] = 0x3F80;
    one = c.v; }
  #pragma unroll
  for (int i = 0; i < 5; ++i){
    int mt = w4 + i*4;
    if (mt < 17){
      f32x4 d0 = (f32x4)0.f, d1 = (f32x4)0.f;
      #pragma unroll
      for (int s = 0; s < 2; ++s){
        int r = mt*16 + lo;
        bf16x8 a = *(const bf16x8*)(hsm + ((r*128 + s*64 + q*16) ^ ((r & 7) << 4)));
        d0 = MFMA(a, one, d0);
        d1 = MFMA(a, a, d1);
      }
      if (lo == 0){
        #pragma unroll
        for (int j = 0; j < 4; ++j) sred[mt*16 + q*4 + j] = d0[j];
      }
      if ((lo >> 2) == q) sred[272 + mt*16 + lo] = d1[lo & 3];
    }
  }
  __syncthreads();
  if (t < NN){
    float s = 0.f, qq = 0.f;
    #pragma unroll
    for (int bl = 0; bl < 16; ++bl){
      s  += sred[t + 17*bl];
      qq += sred[272 + t + 17*bl];
    }
    atomicAdd(&gSum[t], s);
    atomicAdd(&gSq[t], qq);
  }
}

// ---- pre-cast + weight layout prep ----
// W1T[n][k] = W_p1[k][n]  (row-major [256][1088], 2176B rows — r2 layout).
// W2T[e][k] = W_p2[k][e].  WGT: W1hi,W1lo,W2hi,W2lo transposed gc weights.
__global__ __launch_bounds__(256) void k_prep(const float* __restrict__ Wp1,
                                              const float* __restrict__ Wp2,
                                              const float* __restrict__ Wg1,
                                              const float* __restrict__ Wg2,
                                              ushort16* __restrict__ W1T,
                                              ushort16* __restrict__ W2T,
                                              ushort16* __restrict__ WGT,
                                              float* __restrict__ colsum2){
  int g = blockIdx.x * 256 + threadIdx.x;
  if (g < 278528){
    int n = g / 1088, k = g - n*1088;              // W1T[n][k] = W_p1[k][n]
    W1T[g] = f2bfu(Wp1[(size_t)k*256 + n]);
  } else if (g < 311296){
    int h = g - 278528;
    int e = h >> 8, k = h & 255;
    W2T[h] = f2bfu(Wp2[(size_t)k*128 + e]);
  } else if (g < 327680){
    int h = g - 311296;
    int sel = h >> 12;                 // 0:W1hi 1:W1lo 2:W2hi 3:W2lo
    int idx = h & 4095;
    int e = idx >> 6, d = idx & 63;
    const float* Wsrc = (sel < 2) ? Wg1 : Wg2;
    float v = Wsrc[d*64 + e];
    __hip_bfloat16 hi = __float2bfloat16(v);
    if (sel & 1){
      float rem = v - __bfloat162float(hi);
      WGT[h] = f2bfu(rem);
    } else {
      WGT[h] = f2bfu(v);
    }
  } else {
    int e = g - 327680;
    if (e < 64){
      float cs = 0.f;
      for (int d = 0; d < 64; ++d){
        float v = Wg2[d*64 + e];
        float hi = __bfloat162float(__float2bfloat16(v));
        float lo = __bfloat162float(__float2bfloat16(v - hi));
        cs += hi + lo;
      }
      colsum2[e] = cs;
    }
  }
}

// SH[n*64+e] = shift2[n]*colsum2[e] + b_gc2[e]
__global__ void k_sh(const float* __restrict__ shift2, const float* __restrict__ colsum2,
                     const float* __restrict__ bg2, float* __restrict__ SH){
  int n = blockIdx.x, e = threadIdx.x;
  SH[n*64 + e] = fmaf(shift2[n], colsum2[e], bg2[e]);
}

// ---- pass 1: BN1 statistics over s1 = enc+agg (register + shuffle) ----
__global__ __launch_bounds__(256,4) void k_stats1(const float* __restrict__ x,
    const float* __restrict__ W_enc, const float* __restrict__ b_enc,
    float* __restrict__ gSum, float* __restrict__ gSq){
  __shared__ __align__(16) float xs[1088];     // 32 rows x 34 = 272 float4
  int t = threadIdx.x, e = t & 63, lb = t >> 6;
  float we0 = W_enc[e], we1 = W_enc[64 + e], be = b_enc[e];
  const float4* xg = (const float4*)(x + (size_t)blockIdx.x*1088);
  ((float4*)xs)[t] = xg[t];
  if (t < 16) ((float4*)xs)[256 + t] = xg[256 + t];   // tail: 272 float4 > 256 threads
  float sA[NN], qA[NN];
  #pragma unroll
  for (int n = 0; n < NN; ++n){ sA[n] = 0.f; qA[n] = 0.f; }
  __syncthreads();
  for (int it = 0; it < 8; ++it){
    float s1[NN];
    enc_agg(xs + (it*4 + lb)*34, we0, we1, be, s1);
    #pragma unroll
    for (int n = 0; n < NN; ++n){ sA[n] += s1[n]; qA[n] += s1[n]*s1[n]; }
  }
  int slot = (blockIdx.x & 31) * 32;
  reduce_stats(sA, qA, gSum + slot, gSq + slot);
}

__global__ void k_finalize(const float* __restrict__ gSum, const float* __restrict__ gSq,
                           const float* __restrict__ gamma, const float* __restrict__ beta,
                           float* __restrict__ scale, float* __restrict__ shift){
  int n = threadIdx.x;
  if (n < NN){
    float s = 0.f, qq = 0.f;
    for (int sl = 0; sl < 32; ++sl){ s += gSum[sl*32 + n]; qq += gSq[sl*32 + n]; }
    const float invC = 1.0f / (float)((size_t)B_TOTAL * 64);
    float mean = s * invC;
    float var  = qq * invC - mean*mean;
    float istd = rsqrtf(var + 1e-5f);
    float sc   = gamma[n] * istd;
    scale[n] = sc;
    shift[n] = fmaf(-mean, sc, beta[n]);
  }
}

// ---- pass 2: enc+agg, BN1 -> hn(bf16 LDS), MFMA gc1, relu, agg -> S + BN2 stats ----
__global__ __launch_bounds__(256,4) void k_gc1(const float* __restrict__ x,
    const float* __restrict__ W_enc, const float* __restrict__ b_enc,
    const float* __restrict__ bg,
    const float* __restrict__ scale, const float* __restrict__ shift,
    const __hip_bfloat16* __restrict__ Whi, const __hip_bfloat16* __restrict__ Wlo,
    __hip_bfloat16* __restrict__ S, float* __restrict__ gSum, float* __restrict__ gSq){
  __shared__ __align__(16) char hsm[272*128];
  __shared__ float sred[544];
  __shared__ __align__(16) float xs[544];      // 16 rows x 34 = 136 float4
  __shared__ float sc_s[NN], sf_s[NN];
  const int t = threadIdx.x, e = t & 63, lb = t >> 6;
  const int w4 = t >> 6, lo = t & 15, q = (t >> 4) & 3;
  if (t < NN){ sc_s[t] = scale[t]; sf_s[t] = shift[t]; }
  if (t < 136) ((float4*)xs)[t] = ((const float4*)(x + (size_t)blockIdx.x*544))[t];
  float we0 = W_enc[e], we1 = W_enc[64 + e], be = b_enc[e];
  __syncthreads();

  // phase 1: enc + agg + BN1-apply -> hn bf16 LDS
  for (int it = 0; it < 4; ++it){
    int bl = it*4 + lb;
    float s1[NN];
    enc_agg(xs + bl*34, we0, we1, be, s1);
    #pragma unroll
    for (int n = 0; n < NN; ++n){
      int row = bl*17 + n;
      int byt = (row*128 + 2*e) ^ ((row & 7) << 4);
      *(__hip_bfloat16*)(hsm + byt) = __float2bfloat16(fmaf(s1[n], sc_s[n], sf_s[n]));
    }
  }
  __syncthreads();

  // phase 2: h2 = hn @ (Whi + Wlo)
  const char* WhiB = (const char*)Whi;
  const char* WloB = (const char*)Wlo;
  f32x4 acc[5][4];
  #pragma unroll
  for (int i = 0; i < 5; ++i)
    #pragma unroll
    for (int et = 0; et < 4; ++et) acc[i][et] = (f32x4)0.f;
  #pragma unroll
  for (int et = 0; et < 4; ++et){
    int col = et*16 + lo;
    bf16x8 wh0 = *(const bf16x8*)(WhiB + col*128 +      q*16);
    bf16x8 wh1 = *(const bf16x8*)(WhiB + col*128 + 64 + q*16);
    bf16x8 wl0 = *(const bf16x8*)(WloB + col*128 +      q*16);
    bf16x8 wl1 = *(const bf16x8*)(WloB + col*128 + 64 + q*16);
    #pragma unroll
    for (int i = 0; i < 5; ++i){
      int mt = w4 + i*4;
      if (mt < 17){
        int r = mt*16 + lo;
        int base = r*128, sw = (r & 7) << 4;
        bf16x8 a0 = *(const bf16x8*)(hsm + ((base +      q*16) ^ sw));
        bf16x8 a1 = *(const bf16x8*)(hsm + ((base + 64 + q*16) ^ sw));
        acc[i][et] = MFMA(a0, wh0, acc[i][et]);
        acc[i][et] = MFMA(a1, wh1, acc[i][et]);
        acc[i][et] = MFMA(a0, wl0, acc[i][et]);
        acc[i][et] = MFMA(a1, wl1, acc[i][et]);
      }
    }
  }
  float bgv[4];
  #pragma unroll
  for (int et = 0; et < 4; ++et) bgv[et] = bg[et*16 + lo];
  __syncthreads();

  // writeback: h2 = relu(acc + bias) -> reuse hsm
  #pragma unroll
  for (int i = 0; i < 5; ++i){
    int mt = w4 + i*4;
    if (mt < 17){
      #pragma unroll
      for (int et = 0; et < 4; ++et){
        #pragma unroll
        for (int j = 0; j < 4; ++j){
          int row = mt*16 + q*4 + j;
          float h2 = fmaxf(acc[i][et][j] + bgv[et], 0.f);
          int byt = (row*128 + (et*16 + lo)*2) ^ ((row & 7) << 4);
          *(__hip_bfloat16*)(hsm + byt) = __float2bfloat16(h2);
        }
      }
    }
  }
  __syncthreads();

  // phase 3: aggregate -> s2, write bf16 in place
  for (int it = 0; it < 4; ++it){
    int bl = it*4 + lb;
    int row0 = bl*17;
    float h2v[NN];
    #pragma unroll
    for (int n = 0; n < NN; ++n){
      int row = row0 + n;
      h2v[n] = __bfloat162float(*(const __hip_bfloat16*)(hsm + ((row*128 + 2*e) ^ ((row & 7) << 4))));
    }
    #pragma unroll
    for (int n = 0; n < NN; ++n){
      float agg = 0.f;
      #pragma unroll
      for (int j = 0; j < 4; ++j) if (j < CNT[n]) agg += h2v[NBR[n][j]];
      float s2 = fmaf(INVDEG[n], agg, h2v[n]);
      int row = row0 + n;
      *(__hip_bfloat16*)(hsm + ((row*128 + 2*e) ^ ((row & 7) << 4))) = __float2bfloat16(s2);
    }
  }
  __syncthreads();

  // BN2 stats via MFMA (slot-spread atomics)
  int slot = (blockIdx.x & 31) * 32;
  mfma_stats(hsm, sred, t, gSum + slot, gSq + slot);

  // coalesced copy of the 272x128B tile -> S
  const size_t gbase = (size_t)blockIdx.x * 34816;
  char* Sc = (char*)S;
  #pragma unroll
  for (int k = 0; k < 9; ++k){
    int g = t + k*256;
    if (g < 2176){
      int row = g >> 3;
      uint4 v = *(const uint4*)(hsm + ((g*16) ^ ((row & 7) << 4)));
      *(uint4*)(Sc + gbase + (size_t)g*16) = v;
    }
  }
}

// ---- pass 3: fused gc2 + pooled MLP + L2 normalize (r2-verified version) ----
// Per block: 128 batch rows. Per node n: gc2 via operand-swapped MFMA
//   D[e][b] = sum_d W2T[e][d] * s2[b][d]   (A = WG2 hi/lo frags, B = s2 straight
//   from global, 16B frags). BN2 folded into output: h3 = relu(sc2[n]*D + SH[n][e]).
// P tile (128 x 64 bf16, XOR-swizzled, double-buffered) feeds the mlp k-loop.
__global__ __launch_bounds__(256,2) void k_back(
    const __hip_bfloat16* __restrict__ S,
    const ushort16* __restrict__ W1T, const float* __restrict__ b_p1,
    const ushort16* __restrict__ W2T, const float* __restrict__ b_p2,
    const __hip_bfloat16* __restrict__ WG2,   // hi; lo at +4096 elems
    const float* __restrict__ scale2, const float* __restrict__ SH,
    float* __restrict__ out){
  __shared__ __align__(16) char smem[65536];
  const int t = threadIdx.x;
  const int L = t & 63, w = t >> 6;
  const int lo = L & 15, q = L >> 4;
  const size_t b0 = (size_t)blockIdx.x * 128;
  const char* Sb  = (const char*)S;
  const char* W1b = (const char*)W1T;
  const char* W2b = (const char*)W2T;
  const char* Wgb = (const char*)WG2;   // [e][d], 128B rows; lo plane at +8192 bytes

  f32x4 acc[16][2];
  #pragma unroll
  for (int nt = 0; nt < 16; ++nt){ acc[nt][0] = (f32x4)0.f; acc[nt][1] = (f32x4)0.f; }

  uint4 wr0, wr1, wr2, wr3;
  auto loadW = [&](int ks){
    size_t kb = (size_t)ks * 64;
    wr0 = *(const uint4*)(W1b + (size_t)((  0 + t) >> 2)*2176 + kb + (t&3)*16);
    wr1 = *(const uint4*)(W1b + (size_t)((256 + t) >> 2)*2176 + kb + (t&3)*16);
    wr2 = *(const uint4*)(W1b + (size_t)((512 + t) >> 2)*2176 + kb + (t&3)*16);
    wr3 = *(const uint4*)(W1b + (size_t)((768 + t) >> 2)*2176 + kb + (t&3)*16);
  };
  auto writeW = [&](int buf){
    char* Wb = smem + 32768 + (buf ? 16384 : 0);
    *(uint4*)(Wb + (size_t)t*16)          = wr0;
    *(uint4*)(Wb + (size_t)(256 + t)*16)  = wr1;
    *(uint4*)(Wb + (size_t)(512 + t)*16)  = wr2;
    *(uint4*)(Wb + (size_t)(768 + t)*16)  = wr3;
  };

  uint4 br[4];
  auto loadS2 = [&](int n){
    const char* base = Sb + (b0 + (size_t)(w*32 + lo))*2176 + n*128 + q*16;
    br[0] = *(const uint4*)(base);
    br[1] = *(const uint4*)(base + 64);
    br[2] = *(const uint4*)(base + 16*2176);
    br[3] = *(const uint4*)(base + 16*2176 + 64);
  };
  auto gc2w = [&](int n){
    char* Pb = smem + (n & 1)*16384;
    float sc = scale2[n];
    f32x4 g[2][4];
    #pragma unroll
    for (int bt = 0; bt < 2; ++bt)
      #pragma unroll
      for (int et = 0; et < 4; ++et) g[bt][et] = (f32x4)0.f;
    #pragma unroll
    for (int et = 0; et < 4; ++et){
      const char* A = Wgb + (et*16 + lo)*128 + q*16;
      bf16x8 ah0 = *(const bf16x8*)(A);
      bf16x8 ah1 = *(const bf16x8*)(A + 64);
      bf16x8 al0 = *(const bf16x8*)(A + 8192);
      bf16x8 al1 = *(const bf16x8*)(A + 8192 + 64);
      #pragma unroll
      for (int bt = 0; bt < 2; ++bt){
        union { uint4 u; bf16x8 v; } c0, c1;
        c0.u = br[bt*2]; c1.u = br[bt*2 + 1];
        g[bt][et] = MFMA(ah0, c0.v, g[bt][et]);
        g[bt][et] = MFMA(al0, c0.v, g[bt][et]);
        g[bt][et] = MFMA(ah1, c1.v, g[bt][et]);
        g[bt][et] = MFMA(al1, c1.v, g[bt][et]);
      }
    }
    #pragma unroll
    for (int et = 0; et < 4; ++et){
      float4 sh4 = *(const float4*)&SH[n*64 + et*16 + q*4];
      #pragma unroll
      for (int bt = 0; bt < 2; ++bt){
        int b = w*32 + bt*16 + lo;
        float v0 = fmaxf(fmaf(sc, g[bt][et].x, sh4.x), 0.f);
        float v1 = fmaxf(fmaf(sc, g[bt][et].y, sh4.y), 0.f);
        float v2 = fmaxf(fmaf(sc, g[bt][et].z, sh4.z), 0.f);
        float v3 = fmaxf(fmaf(sc, g[bt][et].w, sh4.w), 0.f);
        uint32 u0 = (uint32)f2bfu(v0) | ((uint32)f2bfu(v1) << 16);
        uint32 u1 = (uint32)f2bfu(v2) | ((uint32)f2bfu(v3) << 16);
        int byt = (b*128 + (et*16 + q*4)*2) ^ ((b & 7) << 4);
        *(uint2*)(Pb + byt) = make_uint2(u0, u1);
      }
    }
  };

  loadW(0);
  loadS2(0);
  gc2w(0);
  writeW(0);
  __syncthreads();

  #pragma unroll 1
  for (int ks = 0; ks < 34; ++ks){
    const int cur = ks & 1, n = ks >> 1, half = ks & 1;
    if (ks < 33) loadW(ks + 1);
    if (half == 0 && n < 16) loadS2(n + 1);
    const char* Pb = smem + (n & 1)*16384;
    const char* Wb = smem + 32768 + (cur ? 16384 : 0);
    int r0 = w*32 + lo, r1 = w*32 + 16 + lo;
    bf16x8 pf0 = *(const bf16x8*)(Pb + ((r0*128 + half*64 + q*16) ^ ((r0 & 7) << 4)));
    bf16x8 pf1 = *(const bf16x8*)(Pb + ((r1*128 + half*64 + q*16) ^ ((r1 & 7) << 4)));
    #pragma unroll
    for (int nt = 0; nt < 16; ++nt){
      bf16x8 wf = *(const bf16x8*)(Wb + (nt*16 + lo)*64 + q*16);
      acc[nt][0] = MFMA(wf, pf0, acc[nt][0]);
      acc[nt][1] = MFMA(wf, pf1, acc[nt][1]);
    }
    if (half == 1 && n < 16) gc2w(n + 1);   // writes the OTHER P buffer
    if (ks < 33) writeW(cur ^ 1);
    __syncthreads();
  }

  // epilogue 1: z = relu(z^T + b_p1) -> LDS bf16 [b][256], 8B-granule XOR swizzle by (b&7)
  #pragma unroll
  for (int nt = 0; nt < 16; ++nt){
    float4 bias = *(const float4*)&b_p1[nt*16 + q*4];
    #pragma unroll
    for (int bt = 0; bt < 2; ++bt){
      int b = w*32 + bt*16 + lo;
      f32x4 v = acc[nt][bt];
      float z0 = fmaxf(v.x + bias.x, 0.f), z1 = fmaxf(v.y + bias.y, 0.f);
      float z2 = fmaxf(v.z + bias.z, 0.f), z3 = fmaxf(v.w + bias.w, 0.f);
      uint32 lo32 = (uint32)f2bfu(z0) | ((uint32)f2bfu(z1) << 16);
      uint32 hi32 = (uint32)f2bfu(z2) | ((uint32)f2bfu(z3) << 16);
      int nbyte = (nt*16 + q*4) * 2;
      int addr = b*512 + (nbyte ^ ((b & 7) << 4));
      *(uint2*)(smem + addr) = make_uint2(lo32, hi32);
    }
  }
  __syncthreads();

  // phase 2: emb^T = W2T @ z^T  (K=256, 8 k-steps)
  f32x4 acc2[8][2];
  #pragma unroll
  for (int et = 0; et < 8; ++et){ acc2[et][0] = (f32x4)0.f; acc2[et][1] = (f32x4)0.f; }
  #pragma unroll 1
  for (int ks = 0; ks < 8; ++ks){
    bf16x8 zf0, zf1;
    {
      int b = w*32 + lo;
      int kb = ks*64 + q*16;
      zf0 = *(const bf16x8*)(smem + b*512 + (kb ^ ((b & 7) << 4)));
      b = w*32 + 16 + lo;
      zf1 = *(const bf16x8*)(smem + b*512 + (kb ^ ((b & 7) << 4)));
    }
    #pragma unroll
    for (int et = 0; et < 8; ++et){
      bf16x8 wf = *(const bf16x8*)(W2b + (et*16 + lo)*512 + ks*64 + q*16);
      acc2[et][0] = MFMA(wf, zf0, acc2[et][0]);
      acc2[et][1] = MFMA(wf, zf1, acc2[et][1]);
    }
  }

  // epilogue 2: + b_p2, L2-normalize rows (b), float4 stores
  #pragma unroll
  for (int bt = 0; bt < 2; ++bt){
    int b = w*32 + bt*16 + lo;
    float4 vv[8];
    float ss = 0.f;
    #pragma unroll
    for (int et = 0; et < 8; ++et){
      float4 bias = *(const float4*)&b_p2[et*16 + q*4];
      f32x4 a = bt ? acc2[et][1] : acc2[et][0];
      vv[et].x = a.x + bias.x; vv[et].y = a.y + bias.y;
      vv[et].z = a.z + bias.z; vv[et].w = a.w + bias.w;
      ss += vv[et].x*vv[et].x + vv[et].y*vv[et].y + vv[et].z*vv[et].z + vv[et].w*vv[et].w;
    }
    ss += __shfl_xor(ss, 16, 64);
    ss += __shfl_xor(ss, 32, 64);
    float inv = 1.0f / fmaxf(sqrtf(ss), 1e-12f);
    float* op = out + (b0 + b)*128;
    #pragma unroll
    for (int et = 0; et < 8; ++et){
      float4 o; o.x = vv[et].x*inv; o.y = vv[et].y*inv; o.z = vv[et].z*inv; o.w = vv[et].w*inv;
      *(float4*)(op + et*16 + q*4) = o;
    }
  }
}

extern "C" void kernel_launch(void* const* d_in, const int* in_sizes, int n_in,
                              void* d_out, int out_size, void* d_ws, size_t ws_size,
                              hipStream_t stream) {
  const float* x     = (const float*)d_in[0];
  const float* W_enc = (const float*)d_in[1];
  const float* b_enc = (const float*)d_in[2];
  const float* W_gc1 = (const float*)d_in[3];
  const float* b_gc1 = (const float*)d_in[4];
  const float* W_gc2 = (const float*)d_in[5];
  const float* b_gc2 = (const float*)d_in[6];
  const float* gamma1= (const float*)d_in[7];
  const float* beta1 = (const float*)d_in[8];
  const float* gamma2= (const float*)d_in[9];
  const float* beta2 = (const float*)d_in[10];
  const float* W_p1  = (const float*)d_in[11];
  const float* b_p1  = (const float*)d_in[12];
  const float* W_p2  = (const float*)d_in[13];
  const float* b_p2  = (const float*)d_in[14];
  float* out = (float*)d_out;

  char* ws = (char*)d_ws;
  __hip_bfloat16* S = (__hip_bfloat16*)ws;
  float*    stats = (float*)(ws + STATS_OFF);
  ushort16* W1T   = (ushort16*)(ws + W1_OFF);
  ushort16* W2T   = (ushort16*)(ws + W2_OFF);
  __hip_bfloat16* WGT = (__hip_bfloat16*)(ws + WGT_OFF);

  (void)hipMemsetAsync(stats, 0, 16384, stream);

  k_prep<<<1281, 256, 0, stream>>>(W_p1, W_p2, W_gc1, W_gc2, W1T, W2T,
                                   (ushort16*)WGT, stats + 4224);
  k_stats1<<<2048, 256, 0, stream>>>(x, W_enc, b_enc, stats + 0, stats + 1024);
  k_finalize<<<1, 32, 0, stream>>>(stats + 0, stats + 1024, gamma1, beta1,
                                   stats + 4096, stats + 4128);
  k_gc1<<<4096, 256, 0, stream>>>(x, W_enc, b_enc, b_gc1,
                                  stats + 4096, stats + 4128,
                                  WGT, WGT + 4096,
                                  S, stats + 2048, stats + 3072);
  k_finalize<<<1, 32, 0, stream>>>(stats + 2048, stats + 3072, gamma2, beta2,
                                   stats + 4160, stats + 4192);
  k_sh<<<17, 64, 0, stream>>>(stats + 4192, stats + 4224, b_gc2, stats + 4288);
  k_back<<<512, 256, 0, stream>>>(S, W1T, b_p1, W2T, b_p2,
                                  WGT + 8192, stats + 4160, stats + 4288, out);
}

// Round 9
// 322.476 us; speedup vs baseline: 1.5561x; 1.0261x over previous
//
#include <hip/hip_runtime.h>
#include <hip/hip_bf16.h>

typedef unsigned int  uint32;
typedef unsigned short ushort16;

#define B_TOTAL 65536
#define NN 17

typedef __bf16 bf16x8 __attribute__((ext_vector_type(8)));
typedef float  f32x4  __attribute__((ext_vector_type(4)));

// ---- fixed normalized adjacency (from EDGES in the reference) ----
static constexpr int   CNT[NN]    = {2,0,0,0,0,4,4,2,2,1,1,3,3,2,2,1,1};
static constexpr int   NBR[NN][4] = {
  {5,6,0,0},{0,0,0,0},{0,0,0,0},{0,0,0,0},{0,0,0,0},
  {7,6,11,0},{8,5,12,0},{5,9,0,0},{6,10,0,0},{7,0,0,0},{8,0,0,0},
  {5,12,13,0},{6,11,14,0},{11,15,0,0},{12,16,0,0},{13,0,0,0},{14,0,0,0}};
static constexpr float INVDEG[NN] = {0.5f,0.f,0.f,0.f,0.f,0.25f,0.25f,0.5f,0.5f,1.f,1.f,
  0.33333333333333333f,0.33333333333333333f,0.5f,0.5f,1.f,1.f};

// ---- workspace layout (bytes) ----
#define S_BYTES   ((size_t)B_TOTAL * 1088 * 2)
#define STATS_OFF S_BYTES
#define W1_OFF    (STATS_OFF + 40960)
#define W2_OFF    (W1_OFF + (size_t)278528*2)
#define WGT_OFF   (W2_OFF + (size_t)65536)   // 4 x 4096 bf16: W1hi, W1lo, W2hi, W2lo

// stats float offsets:
//   0     sum1[32 slots][32]      1024  sq1[32][32]
//   2048  sum2[32][32]            3072  sq2[32][32]
//   4096  sc1[32]  4128 sf1[32]   4160  sc2[32]  4192 sf2[32]
//   4224  colsum2[64]             4288  SH[1088]

__device__ inline ushort16 f2bfu(float f){
  union { __hip_bfloat16 h; ushort16 u; } c; c.h = __float2bfloat16(f); return c.u;
}

__device__ inline f32x4 MFMA(bf16x8 a, bf16x8 b, f32x4 c){
  return __builtin_amdgcn_mfma_f32_16x16x32_bf16(a, b, c, 0, 0, 0);
}

__device__ inline void gload_lds16(const void* g, void* l){
  __builtin_amdgcn_global_load_lds(
      (const __attribute__((address_space(1))) unsigned int*)g,
      (__attribute__((address_space(3))) unsigned int*)l, 16, 0, 0);
}

// encoder + normalized-adjacency aggregate for one batch row, one feature dim e.
__device__ inline void enc_agg(const float* __restrict__ xb,
                               float we0, float we1, float be, float* s1){
  float h[NN];
  #pragma unroll
  for (int n = 0; n < NN; ++n)
    h[n] = fmaxf(fmaf(xb[2*n], we0, fmaf(xb[2*n+1], we1, be)), 0.f);
  #pragma unroll
  for (int n = 0; n < NN; ++n){
    float a = 0.f;
    #pragma unroll
    for (int j = 0; j < 4; ++j) if (j < CNT[n]) a += h[NBR[n][j]];
    s1[n] = fmaf(INVDEG[n], a, h[n]);
  }
}

// wave-shuffle BN-stat reduction, atomics spread over slots by caller.
__device__ inline void reduce_stats(float* sA, float* qA,
                                    float* __restrict__ gSum, float* __restrict__ gSq){
  int t = threadIdx.x;
  #pragma unroll
  for (int n = 0; n < NN; ++n){
    float s = sA[n], q = qA[n];
    #pragma unroll
    for (int off = 32; off > 0; off >>= 1){
      s += __shfl_down(s, off, 64);
      q += __shfl_down(q, off, 64);
    }
    sA[n] = s; qA[n] = q;
  }
  __shared__ float shS[NN], shQ[NN];
  if (t < NN){ shS[t] = 0.f; shQ[t] = 0.f; }
  __syncthreads();
  if ((t & 63) == 0){
    #pragma unroll
    for (int n = 0; n < NN; ++n){ atomicAdd(&shS[n], sA[n]); atomicAdd(&shQ[n], qA[n]); }
  }
  __syncthreads();
  if (t < NN){ atomicAdd(&gSum[t], shS[t]); atomicAdd(&gSq[t], shQ[t]); }
}

// ---- MFMA-based BN stats over a 272x64 bf16 LDS tile (XOR-swizzled rows) ----
__device__ inline void mfma_stats(const char* hsm, float* sred, int t,
                                  float* __restrict__ gSum, float* __restrict__ gSq){
  const int w4 = t >> 6, lo = t & 15, q = (t >> 4) & 3;
  bf16x8 one;
  { union { ushort16 u[8]; bf16x8 v; } c;
    #pragma unroll
    for (int i = 0; i < 8; ++i) c.u[i] = 0x3F80;
    one = c.v; }
  #pragma unroll
  for (int i = 0; i < 5; ++i){
    int mt = w4 + i*4;
    if (mt < 17){
      f32x4 d0 = (f32x4)0.f, d1 = (f32x4)0.f;
      #pragma unroll
      for (int s = 0; s < 2; ++s){
        int r = mt*16 + lo;
        bf16x8 a = *(const bf16x8*)(hsm + ((r*128 + s*64 + q*16) ^ ((r & 7) << 4)));
        d0 = MFMA(a, one, d0);
        d1 = MFMA(a, a, d1);
      }
      if (lo == 0){
        #pragma unroll
        for (int j = 0; j < 4; ++j) sred[mt*16 + q*4 + j] = d0[j];
      }
      if ((lo >> 2) == q) sred[272 + mt*16 + lo] = d1[lo & 3];
    }
  }
  __syncthreads();
  if (t < NN){
    float s = 0.f, qq = 0.f;
    #pragma unroll
    for (int bl = 0; bl < 16; ++bl){
      s  += sred[t + 17*bl];
      qq += sred[272 + t + 17*bl];
    }
    atomicAdd(&gSum[t], s);
    atomicAdd(&gSq[t], qq);
  }
}

// ---- pre-cast + weight layout prep ----
// W1T[n][k] = W_p1[k][n]  (row-major [256][1088], 2176B rows — r2 layout).
// W2T[e][k] = W_p2[k][e].  WGT: W1hi,W1lo,W2hi,W2lo transposed gc weights.
__global__ __launch_bounds__(256) void k_prep(const float* __restrict__ Wp1,
                                              const float* __restrict__ Wp2,
                                              const float* __restrict__ Wg1,
                                              const float* __restrict__ Wg2,
                                              ushort16* __restrict__ W1T,
                                              ushort16* __restrict__ W2T,
                                              ushort16* __restrict__ WGT,
                                              float* __restrict__ colsum2){
  int g = blockIdx.x * 256 + threadIdx.x;
  if (g < 278528){
    int n = g / 1088, k = g - n*1088;              // W1T[n][k] = W_p1[k][n]
    W1T[g] = f2bfu(Wp1[(size_t)k*256 + n]);
  } else if (g < 311296){
    int h = g - 278528;
    int e = h >> 8, k = h & 255;
    W2T[h] = f2bfu(Wp2[(size_t)k*128 + e]);
  } else if (g < 327680){
    int h = g - 311296;
    int sel = h >> 12;                 // 0:W1hi 1:W1lo 2:W2hi 3:W2lo
    int idx = h & 4095;
    int e = idx >> 6, d = idx & 63;
    const float* Wsrc = (sel < 2) ? Wg1 : Wg2;
    float v = Wsrc[d*64 + e];
    __hip_bfloat16 hi = __float2bfloat16(v);
    if (sel & 1){
      float rem = v - __bfloat162float(hi);
      WGT[h] = f2bfu(rem);
    } else {
      WGT[h] = f2bfu(v);
    }
  } else {
    int e = g - 327680;
    if (e < 64){
      float cs = 0.f;
      for (int d = 0; d < 64; ++d){
        float v = Wg2[d*64 + e];
        float hi = __bfloat162float(__float2bfloat16(v));
        float lo = __bfloat162float(__float2bfloat16(v - hi));
        cs += hi + lo;
      }
      colsum2[e] = cs;
    }
  }
}

// SH[n*64+e] = shift2[n]*colsum2[e] + b_gc2[e]
__global__ void k_sh(const float* __restrict__ shift2, const float* __restrict__ colsum2,
                     const float* __restrict__ bg2, float* __restrict__ SH){
  int n = blockIdx.x, e = threadIdx.x;
  SH[n*64 + e] = fmaf(shift2[n], colsum2[e], bg2[e]);
}

// ---- pass 1: BN1 statistics over s1 = enc+agg (register + shuffle) ----
__global__ __launch_bounds__(256,4) void k_stats1(const float* __restrict__ x,
    const float* __restrict__ W_enc, const float* __restrict__ b_enc,
    float* __restrict__ gSum, float* __restrict__ gSq){
  __shared__ __align__(16) float xs[1088];     // 32 rows x 34 = 272 float4
  int t = threadIdx.x, e = t & 63, lb = t >> 6;
  float we0 = W_enc[e], we1 = W_enc[64 + e], be = b_enc[e];
  const float4* xg = (const float4*)(x + (size_t)blockIdx.x*1088);
  ((float4*)xs)[t] = xg[t];
  if (t < 16) ((float4*)xs)[256 + t] = xg[256 + t];   // tail: 272 float4 > 256 threads
  float sA[NN], qA[NN];
  #pragma unroll
  for (int n = 0; n < NN; ++n){ sA[n] = 0.f; qA[n] = 0.f; }
  __syncthreads();
  for (int it = 0; it < 8; ++it){
    float s1[NN];
    enc_agg(xs + (it*4 + lb)*34, we0, we1, be, s1);
    #pragma unroll
    for (int n = 0; n < NN; ++n){ sA[n] += s1[n]; qA[n] += s1[n]*s1[n]; }
  }
  int slot = (blockIdx.x & 31) * 32;
  reduce_stats(sA, qA, gSum + slot, gSq + slot);
}

__global__ void k_finalize(const float* __restrict__ gSum, const float* __restrict__ gSq,
                           const float* __restrict__ gamma, const float* __restrict__ beta,
                           float* __restrict__ scale, float* __restrict__ shift){
  int n = threadIdx.x;
  if (n < NN){
    float s = 0.f, qq = 0.f;
    for (int sl = 0; sl < 32; ++sl){ s += gSum[sl*32 + n]; qq += gSq[sl*32 + n]; }
    const float invC = 1.0f / (float)((size_t)B_TOTAL * 64);
    float mean = s * invC;
    float var  = qq * invC - mean*mean;
    float istd = rsqrtf(var + 1e-5f);
    float sc   = gamma[n] * istd;
    scale[n] = sc;
    shift[n] = fmaf(-mean, sc, beta[n]);
  }
}

// ---- pass 2: enc+agg, BN1 -> hn(bf16 LDS), MFMA gc1, relu, agg -> S + BN2 stats ----
__global__ __launch_bounds__(256,4) void k_gc1(const float* __restrict__ x,
    const float* __restrict__ W_enc, const float* __restrict__ b_enc,
    const float* __restrict__ bg,
    const float* __restrict__ scale, const float* __restrict__ shift,
    const __hip_bfloat16* __restrict__ Whi, const __hip_bfloat16* __restrict__ Wlo,
    __hip_bfloat16* __restrict__ S, float* __restrict__ gSum, float* __restrict__ gSq){
  __shared__ __align__(16) char hsm[272*128];
  __shared__ float sred[544];
  __shared__ __align__(16) float xs[544];      // 16 rows x 34 = 136 float4
  __shared__ float sc_s[NN], sf_s[NN];
  const int t = threadIdx.x, e = t & 63, lb = t >> 6;
  const int w4 = t >> 6, lo = t & 15, q = (t >> 4) & 3;
  if (t < NN){ sc_s[t] = scale[t]; sf_s[t] = shift[t]; }
  if (t < 136) ((float4*)xs)[t] = ((const float4*)(x + (size_t)blockIdx.x*544))[t];
  float we0 = W_enc[e], we1 = W_enc[64 + e], be = b_enc[e];
  __syncthreads();

  // phase 1: enc + agg + BN1-apply -> hn bf16 LDS
  for (int it = 0; it < 4; ++it){
    int bl = it*4 + lb;
    float s1[NN];
    enc_agg(xs + bl*34, we0, we1, be, s1);
    #pragma unroll
    for (int n = 0; n < NN; ++n){
      int row = bl*17 + n;
      int byt = (row*128 + 2*e) ^ ((row & 7) << 4);
      *(__hip_bfloat16*)(hsm + byt) = __float2bfloat16(fmaf(s1[n], sc_s[n], sf_s[n]));
    }
  }
  __syncthreads();

  // phase 2: h2 = hn @ (Whi + Wlo)
  const char* WhiB = (const char*)Whi;
  const char* WloB = (const char*)Wlo;
  f32x4 acc[5][4];
  #pragma unroll
  for (int i = 0; i < 5; ++i)
    #pragma unroll
    for (int et = 0; et < 4; ++et) acc[i][et] = (f32x4)0.f;
  #pragma unroll
  for (int et = 0; et < 4; ++et){
    int col = et*16 + lo;
    bf16x8 wh0 = *(const bf16x8*)(WhiB + col*128 +      q*16);
    bf16x8 wh1 = *(const bf16x8*)(WhiB + col*128 + 64 + q*16);
    bf16x8 wl0 = *(const bf16x8*)(WloB + col*128 +      q*16);
    bf16x8 wl1 = *(const bf16x8*)(WloB + col*128 + 64 + q*16);
    #pragma unroll
    for (int i = 0; i < 5; ++i){
      int mt = w4 + i*4;
      if (mt < 17){
        int r = mt*16 + lo;
        int base = r*128, sw = (r & 7) << 4;
        bf16x8 a0 = *(const bf16x8*)(hsm + ((base +      q*16) ^ sw));
        bf16x8 a1 = *(const bf16x8*)(hsm + ((base + 64 + q*16) ^ sw));
        acc[i][et] = MFMA(a0, wh0, acc[i][et]);
        acc[i][et] = MFMA(a1, wh1, acc[i][et]);
        acc[i][et] = MFMA(a0, wl0, acc[i][et]);
        acc[i][et] = MFMA(a1, wl1, acc[i][et]);
      }
    }
  }
  float bgv[4];
  #pragma unroll
  for (int et = 0; et < 4; ++et) bgv[et] = bg[et*16 + lo];
  __syncthreads();

  // writeback: h2 = relu(acc + bias) -> reuse hsm
  #pragma unroll
  for (int i = 0; i < 5; ++i){
    int mt = w4 + i*4;
    if (mt < 17){
      #pragma unroll
      for (int et = 0; et < 4; ++et){
        #pragma unroll
        for (int j = 0; j < 4; ++j){
          int row = mt*16 + q*4 + j;
          float h2 = fmaxf(acc[i][et][j] + bgv[et], 0.f);
          int byt = (row*128 + (et*16 + lo)*2) ^ ((row & 7) << 4);
          *(__hip_bfloat16*)(hsm + byt) = __float2bfloat16(h2);
        }
      }
    }
  }
  __syncthreads();

  // phase 3: aggregate -> s2, write bf16 in place
  for (int it = 0; it < 4; ++it){
    int bl = it*4 + lb;
    int row0 = bl*17;
    float h2v[NN];
    #pragma unroll
    for (int n = 0; n < NN; ++n){
      int row = row0 + n;
      h2v[n] = __bfloat162float(*(const __hip_bfloat16*)(hsm + ((row*128 + 2*e) ^ ((row & 7) << 4))));
    }
    #pragma unroll
    for (int n = 0; n < NN; ++n){
      float agg = 0.f;
      #pragma unroll
      for (int j = 0; j < 4; ++j) if (j < CNT[n]) agg += h2v[NBR[n][j]];
      float s2 = fmaf(INVDEG[n], agg, h2v[n]);
      int row = row0 + n;
      *(__hip_bfloat16*)(hsm + ((row*128 + 2*e) ^ ((row & 7) << 4))) = __float2bfloat16(s2);
    }
  }
  __syncthreads();

  // BN2 stats via MFMA (slot-spread atomics)
  int slot = (blockIdx.x & 31) * 32;
  mfma_stats(hsm, sred, t, gSum + slot, gSq + slot);

  // coalesced copy of the 272x128B tile -> S
  const size_t gbase = (size_t)blockIdx.x * 34816;
  char* Sc = (char*)S;
  #pragma unroll
  for (int k = 0; k < 9; ++k){
    int g = t + k*256;
    if (g < 2176){
      int row = g >> 3;
      uint4 v = *(const uint4*)(hsm + ((g*16) ^ ((row & 7) << 4)));
      *(uint4*)(Sc + gbase + (size_t)g*16) = v;
    }
  }
}

// ---- pass 3: fused gc2 + pooled MLP + L2 normalize ----
// r2 geometry + two latency cuts:
//  (1) WG2 hi/lo fragments are node-invariant -> hoisted to 64 VGPRs at
//      prologue; gc2w is now pure register-MFMA + P-writes (no global loads
//      on the odd-ks tail). gc2w restructured to bt-sequential (g[4]) to
//      keep peak VGPR ~240.
//  (2) W staging via global_load_lds DMA (wave-uniform LDS base + lane*16)
//      -> no wr regs, no vmcnt->ds_write serialization; drains at barrier.
__global__ __launch_bounds__(256,2) void k_back(
    const __hip_bfloat16* __restrict__ S,
    const ushort16* __restrict__ W1T, const float* __restrict__ b_p1,
    const ushort16* __restrict__ W2T, const float* __restrict__ b_p2,
    const __hip_bfloat16* __restrict__ WG2,   // hi; lo at +4096 elems
    const float* __restrict__ scale2, const float* __restrict__ SH,
    float* __restrict__ out){
  __shared__ __align__(16) char smem[65536];
  const int t = threadIdx.x;
  const int L = t & 63, w = t >> 6;
  const int lo = L & 15, q = L >> 4;
  const size_t b0 = (size_t)blockIdx.x * 128;
  const char* Sb  = (const char*)S;
  const char* W1b = (const char*)W1T;
  const char* W2b = (const char*)W2T;
  const char* Wgb = (const char*)WG2;   // [e][d], 128B rows; lo plane at +8192 bytes

  f32x4 acc[16][2];
  #pragma unroll
  for (int nt = 0; nt < 16; ++nt){ acc[nt][0] = (f32x4)0.f; acc[nt][1] = (f32x4)0.f; }

  // ---- WG2 fragments: node-invariant, hoisted to registers once ----
  bf16x8 wg[4][4];   // [et][0]=ah0 [1]=ah1 [2]=al0 [3]=al1 (const idx only)
  #pragma unroll
  for (int et = 0; et < 4; ++et){
    const char* A = Wgb + (et*16 + lo)*128 + q*16;
    wg[et][0] = *(const bf16x8*)(A);
    wg[et][1] = *(const bf16x8*)(A + 64);
    wg[et][2] = *(const bf16x8*)(A + 8192);
    wg[et][3] = *(const bf16x8*)(A + 8192 + 64);
  }

  // ---- W staging via async DMA: dest = (i*256+t)*16 = i*4096 + w*1024 + L*16
  auto stageW = [&](int ks, int buf){
    size_t kb = (size_t)ks * 64;
    char* ldsbase = smem + 32768 + buf*16384 + w*1024;   // wave-uniform
    gload_lds16(W1b + (size_t)((  0 + t) >> 2)*2176 + kb + (t&3)*16, ldsbase);
    gload_lds16(W1b + (size_t)((256 + t) >> 2)*2176 + kb + (t&3)*16, ldsbase + 4096);
    gload_lds16(W1b + (size_t)((512 + t) >> 2)*2176 + kb + (t&3)*16, ldsbase + 8192);
    gload_lds16(W1b + (size_t)((768 + t) >> 2)*2176 + kb + (t&3)*16, ldsbase + 12288);
  };

  uint4 br[4];
  auto loadS2 = [&](int n){
    const char* base = Sb + (b0 + (size_t)(w*32 + lo))*2176 + n*128 + q*16;
    br[0] = *(const uint4*)(base);
    br[1] = *(const uint4*)(base + 64);
    br[2] = *(const uint4*)(base + 16*2176);
    br[3] = *(const uint4*)(base + 16*2176 + 64);
  };
  auto gc2w = [&](int n){
    char* Pb = smem + (n & 1)*16384;
    float sc = scale2[n];
    #pragma unroll
    for (int bt = 0; bt < 2; ++bt){
      f32x4 g[4];
      #pragma unroll
      for (int et = 0; et < 4; ++et) g[et] = (f32x4)0.f;
      union { uint4 u; bf16x8 v; } c0, c1;
      c0.u = br[bt*2]; c1.u = br[bt*2 + 1];
      #pragma unroll
      for (int et = 0; et < 4; ++et){
        g[et] = MFMA(wg[et][0], c0.v, g[et]);
        g[et] = MFMA(wg[et][2], c0.v, g[et]);
        g[et] = MFMA(wg[et][1], c1.v, g[et]);
        g[et] = MFMA(wg[et][3], c1.v, g[et]);
      }
      int b = w*32 + bt*16 + lo;
      #pragma unroll
      for (int et = 0; et < 4; ++et){
        float4 sh4 = *(const float4*)&SH[n*64 + et*16 + q*4];
        float v0 = fmaxf(fmaf(sc, g[et].x, sh4.x), 0.f);
        float v1 = fmaxf(fmaf(sc, g[et].y, sh4.y), 0.f);
        float v2 = fmaxf(fmaf(sc, g[et].z, sh4.z), 0.f);
        float v3 = fmaxf(fmaf(sc, g[et].w, sh4.w), 0.f);
        uint32 u0 = (uint32)f2bfu(v0) | ((uint32)f2bfu(v1) << 16);
        uint32 u1 = (uint32)f2bfu(v2) | ((uint32)f2bfu(v3) << 16);
        int byt = (b*128 + (et*16 + q*4)*2) ^ ((b & 7) << 4);
        *(uint2*)(Pb + byt) = make_uint2(u0, u1);
      }
    }
  };

  loadS2(0);
  gc2w(0);
  stageW(0, 0);
  __syncthreads();   // drains DMA (vmcnt(0) before barrier) + P0 visible

  #pragma unroll 1
  for (int ks = 0; ks < 34; ++ks){
    const int cur = ks & 1, n = ks >> 1, half = ks & 1;
    if (ks < 33) stageW(ks + 1, cur ^ 1);   // async DMA into the other W buf
    if (half == 0 && n < 16) loadS2(n + 1);
    const char* Pb = smem + (n & 1)*16384;
    const char* Wb = smem + 32768 + (cur ? 16384 : 0);
    int r0 = w*32 + lo, r1 = w*32 + 16 + lo;
    bf16x8 pf0 = *(const bf16x8*)(Pb + ((r0*128 + half*64 + q*16) ^ ((r0 & 7) << 4)));
    bf16x8 pf1 = *(const bf16x8*)(Pb + ((r1*128 + half*64 + q*16) ^ ((r1 & 7) << 4)));
    #pragma unroll
    for (int nt = 0; nt < 16; ++nt){
      bf16x8 wf = *(const bf16x8*)(Wb + (nt*16 + lo)*64 + q*16);
      acc[nt][0] = MFMA(wf, pf0, acc[nt][0]);
      acc[nt][1] = MFMA(wf, pf1, acc[nt][1]);
    }
    if (half == 1 && n < 16) gc2w(n + 1);   // pure reg-MFMA now
    __syncthreads();
  }

  // epilogue 1: z = relu(z^T + b_p1) -> LDS bf16 [b][256], 8B-granule XOR swizzle by (b&7)
  #pragma unroll
  for (int nt = 0; nt < 16; ++nt){
    float4 bias = *(const float4*)&b_p1[nt*16 + q*4];
    #pragma unroll
    for (int bt = 0; bt < 2; ++bt){
      int b = w*32 + bt*16 + lo;
      f32x4 v = acc[nt][bt];
      float z0 = fmaxf(v.x + bias.x, 0.f), z1 = fmaxf(v.y + bias.y, 0.f);
      float z2 = fmaxf(v.z + bias.z, 0.f), z3 = fmaxf(v.w + bias.w, 0.f);
      uint32 lo32 = (uint32)f2bfu(z0) | ((uint32)f2bfu(z1) << 16);
      uint32 hi32 = (uint32)f2bfu(z2) | ((uint32)f2bfu(z3) << 16);
      int nbyte = (nt*16 + q*4) * 2;
      int addr = b*512 + (nbyte ^ ((b & 7) << 4));
      *(uint2*)(smem + addr) = make_uint2(lo32, hi32);
    }
  }
  __syncthreads();

  // phase 2: emb^T = W2T @ z^T  (K=256, 8 k-steps)
  f32x4 acc2[8][2];
  #pragma unroll
  for (int et = 0; et < 8; ++et){ acc2[et][0] = (f32x4)0.f; acc2[et][1] = (f32x4)0.f; }
  #pragma unroll 1
  for (int ks = 0; ks < 8; ++ks){
    bf16x8 zf0, zf1;
    {
      int b = w*32 + lo;
      int kb = ks*64 + q*16;
      zf0 = *(const bf16x8*)(smem + b*512 + (kb ^ ((b & 7) << 4)));
      b = w*32 + 16 + lo;
      zf1 = *(const bf16x8*)(smem + b*512 + (kb ^ ((b & 7) << 4)));
    }
    #pragma unroll
    for (int et = 0; et < 8; ++et){
      bf16x8 wf = *(const bf16x8*)(W2b + (et*16 + lo)*512 + ks*64 + q*16);
      acc2[et][0] = MFMA(wf, zf0, acc2[et][0]);
      acc2[et][1] = MFMA(wf, zf1, acc2[et][1]);
    }
  }

  // epilogue 2: + b_p2, L2-normalize rows (b), float4 stores
  #pragma unroll
  for (int bt = 0; bt < 2; ++bt){
    int b = w*32 + bt*16 + lo;
    float4 vv[8];
    float ss = 0.f;
    #pragma unroll
    for (int et = 0; et < 8; ++et){
      float4 bias = *(const float4*)&b_p2[et*16 + q*4];
      f32x4 a = bt ? acc2[et][1] : acc2[et][0];
      vv[et].x = a.x + bias.x; vv[et].y = a.y + bias.y;
      vv[et].z = a.z + bias.z; vv[et].w = a.w + bias.w;
      ss += vv[et].x*vv[et].x + vv[et].y*vv[et].y + vv[et].z*vv[et].z + vv[et].w*vv[et].w;
    }
    ss += __shfl_xor(ss, 16, 64);
    ss += __shfl_xor(ss, 32, 64);
    float inv = 1.0f / fmaxf(sqrtf(ss), 1e-12f);
    float* op = out + (b0 + b)*128;
    #pragma unroll
    for (int et = 0; et < 8; ++et){
      float4 o; o.x = vv[et].x*inv; o.y = vv[et].y*inv; o.z = vv[et].z*inv; o.w = vv[et].w*inv;
      *(float4*)(op + et*16 + q*4) = o;
    }
  }
}

extern "C" void kernel_launch(void* const* d_in, const int* in_sizes, int n_in,
                              void* d_out, int out_size, void* d_ws, size_t ws_size,
                              hipStream_t stream) {
  const float* x     = (const float*)d_in[0];
  const float* W_enc = (const float*)d_in[1];
  const float* b_enc = (const float*)d_in[2];
  const float* W_gc1 = (const float*)d_in[3];
  const float* b_gc1 = (const float*)d_in[4];
  const float* W_gc2 = (const float*)d_in[5];
  const float* b_gc2 = (const float*)d_in[6];
  const float* gamma1= (const float*)d_in[7];
  const float* beta1 = (const float*)d_in[8];
  const float* gamma2= (const float*)d_in[9];
  const float* beta2 = (const float*)d_in[10];
  const float* W_p1  = (const float*)d_in[11];
  const float* b_p1  = (const float*)d_in[12];
  const float* W_p2  = (const float*)d_in[13];
  const float* b_p2  = (const float*)d_in[14];
  float* out = (float*)d_out;

  char* ws = (char*)d_ws;
  __hip_bfloat16* S = (__hip_bfloat16*)ws;
  float*    stats = (float*)(ws + STATS_OFF);
  ushort16* W1T   = (ushort16*)(ws + W1_OFF);
  ushort16* W2T   = (ushort16*)(ws + W2_OFF);
  __hip_bfloat16* WGT = (__hip_bfloat16*)(ws + WGT_OFF);

  (void)hipMemsetAsync(stats, 0, 16384, stream);

  k_prep<<<1281, 256, 0, stream>>>(W_p1, W_p2, W_gc1, W_gc2, W1T, W2T,
                                   (ushort16*)WGT, stats + 4224);
  k_stats1<<<2048, 256, 0, stream>>>(x, W_enc, b_enc, stats + 0, stats + 1024);
  k_finalize<<<1, 32, 0, stream>>>(stats + 0, stats + 1024, gamma1, beta1,
                                   stats + 4096, stats + 4128);
  k_gc1<<<4096, 256, 0, stream>>>(x, W_enc, b_enc, b_gc1,
                                  stats + 4096, stats + 4128,
                                  WGT, WGT + 4096,
                                  S, stats + 2048, stats + 3072);
  k_finalize<<<1, 32, 0, stream>>>(stats + 2048, stats + 3072, gamma2, beta2,
                                   stats + 4160, stats + 4192);
  k_sh<<<17, 64, 0, stream>>>(stats + 4192, stats + 4224, b_gc2, stats + 4288);
  k_back<<<512, 256, 0, stream>>>(S, W1T, b_p1, W2T, b_p2,
                                  WGT + 8192, stats + 4160, stats + 4288, out);
}